// Round 23
// baseline (233.756 us; speedup 1.0000x reference)
//
#include <hip/hip_runtime.h>
#include <hip/hip_fp16.h>
#include <math.h>

#define NN 100000
#define EE 1600000
#define ET (EE + NN)          // edges + self loops = 1,700,000
#define NEG 0.2f
#define SMASK 0x1FFFF

// CSR-build geometry: 196 buckets x 512 dst nodes
#define NBUCK 196
#define NBLK 416              // partition blocks
#define BITEMS 4096           // items per partition block (256 thr x 16)
#define BCAP 10240            // bucket capacity (mean 8676, sigma~93)

typedef float4 f4;
typedef _Float16 h8 __attribute__((ext_vector_type(8)));
typedef float f32x4 __attribute__((ext_vector_type(4)));
typedef unsigned u32x4 __attribute__((ext_vector_type(4)));   // native vec for nontemporal builtins

// ---------------- setup: stats=0, gcnt=0, coef + MFMA weight packing (fused) ----------------
__global__ void k_setup(float* stats, int* gcnt,
                        const float* __restrict__ W1, const float* __restrict__ as1,
                        const float* __restrict__ ad1, float* __restrict__ coef,
                        const float* __restrict__ W2g,
                        const float* __restrict__ w1, const float* __restrict__ w2,
                        const float* __restrict__ w3, const float* __restrict__ w4,
                        const float* __restrict__ w5,
                        _Float16* __restrict__ BH, _Float16* __restrict__ BL,
                        _Float16* __restrict__ BH5, _Float16* __restrict__ BL5) {
    int idx = blockIdx.x * blockDim.x + threadIdx.x;
    if (blockIdx.x == 0) {
        int i = threadIdx.x;
        if (i < 4) stats[i] = 0.f;
        if (i < NBUCK) gcnt[i] = 0;
        if (i >= 248) {                    // threads 248..255 compute coef[0..7]
            int t = i - 248;
            int sd = t >> 2, hh = (t >> 1) & 1, c0 = t & 1;
            const float* a = sd ? ad1 : as1;
            float s = 0.f;
            for (int c = 0; c < 32; ++c) s += W1[(hh * 32 + c) * 2 + c0] * a[hh * 32 + c];
            coef[t] = s;
        }
    }
    if (idx < 5 * 4096) {
        int L = idx >> 12;
        int r = idx & 4095;
        int ks = r >> 11, nt = (r >> 9) & 3, lane = (r >> 3) & 63, j = r & 7;
        const float* W = (L == 0) ? w1 : (L == 1) ? w2 : (L == 2) ? w3 : (L == 3) ? w4 : W2g;
        int n = nt * 16 + (lane & 15);
        int k = ks * 32 + 8 * (lane >> 4) + j;
        float v = W[n * 64 + k];
        _Float16 hi = (_Float16)v;
        BH[idx] = hi;
        BL[idx] = (_Float16)(v - (float)hi);
    }
    if (idx < 1024) {
        int ks = idx >> 9, lane = (idx >> 3) & 63, j = idx & 7;
        int n = lane & 15;
        int k = ks * 32 + 8 * (lane >> 4) + j;
        float v = (n < 11) ? w5[n * 64 + k] : 0.f;
        _Float16 hi = (_Float16)v;
        BH5[idx] = hi;
        BL5[idx] = (_Float16)(v - (float)hi);
    }
}

// ---------------- BN statistics: block-level reduce, 4 atomics/block (64 blocks) ----------------
__global__ void k_bnstats(const float* __restrict__ h, float* stats) {
    __shared__ float red[16];
    int gid = blockIdx.x * blockDim.x + threadIdx.x;
    int stride = gridDim.x * blockDim.x;
    float s0 = 0.f, s1 = 0.f, q0 = 0.f, q1 = 0.f;
    for (int i = gid; i < NN; i += stride) {
        float2 v = reinterpret_cast<const float2*>(h)[i];
        s0 += v.x; q0 += v.x * v.x;
        s1 += v.y; q1 += v.y * v.y;
    }
#pragma unroll
    for (int off = 32; off >= 1; off >>= 1) {
        s0 += __shfl_xor(s0, off);
        s1 += __shfl_xor(s1, off);
        q0 += __shfl_xor(q0, off);
        q1 += __shfl_xor(q1, off);
    }
    int wv = threadIdx.x >> 6;
    if ((threadIdx.x & 63) == 0) {
        red[wv * 4 + 0] = s0; red[wv * 4 + 1] = s1;
        red[wv * 4 + 2] = q0; red[wv * 4 + 3] = q1;
    }
    __syncthreads();
    if (threadIdx.x == 0) {
        float t0 = 0.f, t1 = 0.f, t2 = 0.f, t3 = 0.f;
#pragma unroll
        for (int i = 0; i < 4; ++i) {
            t0 += red[i * 4 + 0]; t1 += red[i * 4 + 1];
            t2 += red[i * 4 + 2]; t3 += red[i * 4 + 3];
        }
        atomicAdd(&stats[0], t0); atomicAdd(&stats[1], t1);
        atomicAdd(&stats[2], t2); atomicAdd(&stats[3], t3);
    }
}

// ---------------- fused CSR partition (nontemporal streams) ----------------
__global__ void __launch_bounds__(256) k_fpart(const int* __restrict__ ei, int* gcnt,
                                               unsigned* __restrict__ pairs) {
    __shared__ int hist[NBUCK];
    __shared__ int cur[NBUCK];
    int tid = threadIdx.x, blk = blockIdx.x;
    if (tid < NBUCK) hist[tid] = 0;
    int ss[16], dd[16];
    int base = blk * BITEMS;
    __syncthreads();
#pragma unroll
    for (int it = 0; it < 16; ++it) {
        int i = base + it * 256 + tid;
        int s = 0, d = -1;
        if (i < ET) {
            if (i < EE) {
                s = __builtin_nontemporal_load(&ei[i]);
                d = __builtin_nontemporal_load(&ei[EE + i]);
            } else { s = d = i - EE; }
            atomicAdd(&hist[d >> 9], 1);
        }
        ss[it] = s; dd[it] = d;
    }
    __syncthreads();
    if (tid < NBUCK) cur[tid] = tid * BCAP + atomicAdd(&gcnt[tid], hist[tid]);
    __syncthreads();
#pragma unroll
    for (int it = 0; it < 16; ++it) {
        int d = dd[it];
        if (d >= 0) {
            int pos = atomicAdd(&cur[d >> 9], 1);
            __builtin_nontemporal_store((unsigned)ss[it] | ((unsigned)(d & 511) << 17),
                                        &pairs[pos]);
        }
    }
}

// ---------------- per-bucket local CSR + fused layer-1 prep ----------------
__global__ void __launch_bounds__(512) k_bucket(const unsigned* __restrict__ pairs,
                                                 const int* __restrict__ gcnt,
                                                 int* __restrict__ rowptr,
                                                 unsigned* __restrict__ srcl,
                                                 const float* __restrict__ h,
                                                 const float* __restrict__ stats,
                                                 const float* __restrict__ gamma,
                                                 const float* __restrict__ beta,
                                                 const float* __restrict__ coef,
                                                 f4* __restrict__ nd1, float2* __restrict__ ed1) {
    __shared__ int sh[512];
    __shared__ int se[512];
    int b = blockIdx.x, tid = threadIdx.x;
    sh[tid] = (tid < b) ? gcnt[tid] : 0;
    __syncthreads();
    for (int off = 256; off >= 1; off >>= 1) {
        if (tid < off) sh[tid] += sh[tid + off];
        __syncthreads();
    }
    int obase = sh[0];
    __syncthreads();
    int cnt = gcnt[b];
    int ibase = b * BCAP;
    sh[tid] = 0;
    __syncthreads();
    for (int k = tid; k < cnt; k += 512) atomicAdd(&sh[pairs[ibase + k] >> 17], 1);
    __syncthreads();
    int deg = sh[tid];
    se[tid] = deg;
    __syncthreads();
    for (int off = 1; off < 512; off <<= 1) {
        int t = (tid >= off) ? se[tid - off] : 0;
        __syncthreads();
        se[tid] += t;
        __syncthreads();
    }
    int excl = se[tid] - deg;
    int node = (b << 9) + tid;
    if (node < NN) rowptr[node] = obase + excl;
    sh[tid] = obase + excl;     // cursor
    __syncthreads();
    for (int k = tid; k < cnt; k += 512) {
        unsigned p = pairs[ibase + k];
        int pos = atomicAdd(&sh[p >> 17], 1);
        __builtin_nontemporal_store(p, &srcl[pos]);
    }
    if (b == 0 && tid == 0) rowptr[NN] = ET;

    // fused layer-1 prep
    if (node < NN) {
        const float inv = 1.f / (float)NN;
        float mu0 = stats[0] * inv, mu1 = stats[1] * inv;
        float v0 = stats[2] * inv - mu0 * mu0;
        float v1 = stats[3] * inv - mu1 * mu1;
        float g0 = rsqrtf(v0 + 1e-5f) * gamma[0];
        float g1 = rsqrtf(v1 + 1e-5f) * gamma[1];
        float2 hv = reinterpret_cast<const float2*>(h)[node];
        float x0 = (hv.x - mu0) * g0 + beta[0];
        float x1 = (hv.y - mu1) * g1 + beta[1];
        nd1[node] = make_float4(x0 * coef[0] + x1 * coef[1], x0 * coef[2] + x1 * coef[3], x0, x1);
        ed1[node] = make_float2(x0 * coef[4] + x1 * coef[5], x0 * coef[6] + x1 * coef[7]);
    }
}

// ---------------- layer-1 GAT: 8 lanes per dst, shfl reduce (nontemporal srcl) ----------------
__global__ void __launch_bounds__(256) k_gat1(
    const f4* __restrict__ nd1, const float2* __restrict__ ed1,
    const int* __restrict__ rowptr, const unsigned* __restrict__ srcl,
    f4* __restrict__ agg1a, float2* __restrict__ agg1s) {
    int gid = blockIdx.x * blockDim.x + threadIdx.x;
    int n = gid >> 3;
    int sub = gid & 7;
    if (n >= NN) return;
    int beg = rowptr[n], end = rowptr[n + 1];
    float2 ed = ed1[n];
    float A0 = 0.f, B0 = 0.f, S0 = 0.f, A1 = 0.f, B1 = 0.f, S1 = 0.f;
    for (int k = beg + sub; k < end; k += 8) {
        int s = (int)(__builtin_nontemporal_load(&srcl[k]) & SMASK);
        f4 p = nd1[s];
        float e0 = p.x + ed.x;
        float e1 = p.y + ed.y;
        e0 = fmaxf(e0, NEG * e0);
        e1 = fmaxf(e1, NEG * e1);
        float w0 = __expf(e0);
        float w1 = __expf(e1);
        A0 += w0 * p.z; B0 += w0 * p.w; S0 += w0;
        A1 += w1 * p.z; B1 += w1 * p.w; S1 += w1;
    }
#pragma unroll
    for (int off = 1; off < 8; off <<= 1) {
        A0 += __shfl_xor(A0, off);
        B0 += __shfl_xor(B0, off);
        S0 += __shfl_xor(S0, off);
        A1 += __shfl_xor(A1, off);
        B1 += __shfl_xor(B1, off);
        S1 += __shfl_xor(S1, off);
    }
    if (sub == 0) {
        agg1a[n] = make_float4(A0, B0, A1, B1);
        agg1s[n] = make_float2(S0, S1);
    }
}

#define MAKE_A(ks)                                                                \
    f4 a0 = *reinterpret_cast<const f4*>(&xw[mrow * 68 + kg * 8 + (ks) * 32]);    \
    f4 a1 = *reinterpret_cast<const f4*>(&xw[mrow * 68 + kg * 8 + (ks) * 32 + 4]);\
    float av0 = a0.x, av1 = a0.y, av2 = a0.z, av3 = a0.w;                         \
    float av4 = a1.x, av5 = a1.y, av6 = a1.z, av7 = a1.w;                         \
    h8 ah, al;                                                                    \
    { _Float16 t;                                                                 \
      t = (_Float16)av0; ah[0] = t; al[0] = (_Float16)(av0 - (float)t);           \
      t = (_Float16)av1; ah[1] = t; al[1] = (_Float16)(av1 - (float)t);           \
      t = (_Float16)av2; ah[2] = t; al[2] = (_Float16)(av2 - (float)t);           \
      t = (_Float16)av3; ah[3] = t; al[3] = (_Float16)(av3 - (float)t);           \
      t = (_Float16)av4; ah[4] = t; al[4] = (_Float16)(av4 - (float)t);           \
      t = (_Float16)av5; ah[5] = t; al[5] = (_Float16)(av5 - (float)t);           \
      t = (_Float16)av6; ah[6] = t; al[6] = (_Float16)(av6 - (float)t);           \
      t = (_Float16)av7; ah[7] = t; al[7] = (_Float16)(av7 - (float)t); }

// ---------------- layer-1 finalize + MFMA linear(64->64) + layer-2 attn scalars ----------------
__global__ void __launch_bounds__(256) k_xform2m(
    const f4* __restrict__ agg1a, const float2* __restrict__ agg1s,
    const float* __restrict__ W1, const float* __restrict__ b1,
    const _Float16* __restrict__ BH2, const _Float16* __restrict__ BL2,
    const float* __restrict__ a_s, const float* __restrict__ a_d,
    __half* __restrict__ xph, float2* __restrict__ es2v, float2* __restrict__ ed2v) {
    __shared__ float xs[4 * 1088];
    int lane = threadIdx.x & 63;
    int w = threadIdx.x >> 6;
    float* xw = &xs[w * 1088];
    int nodeBase = blockIdx.x * 64 + w * 16;
    int mrow = lane & 15;
    int kg = lane >> 4;
    int n = nodeBase + mrow;

    f4 ag = make_float4(0.f, 0.f, 0.f, 0.f);
    float2 sg = make_float2(1.f, 1.f);
    if (n < NN) { ag = agg1a[n]; sg = agg1s[n]; }
    float r0 = 1.f / (sg.x + 1e-16f);
    float r1 = 1.f / (sg.y + 1e-16f);
#pragma unroll
    for (int j = 0; j < 16; ++j) {
        int f = kg * 16 + j;
        float A = (f < 32) ? ag.x : ag.z;
        float B = (f < 32) ? ag.y : ag.w;
        float r = (f < 32) ? r0 : r1;
        xw[mrow * 68 + f] = fmaxf((A * W1[2 * f] + B * W1[2 * f + 1]) * r + b1[f], 0.f);
    }
    __syncthreads();

    const h8* bh = reinterpret_cast<const h8*>(BH2);
    const h8* bl = reinterpret_cast<const h8*>(BL2);
    h8 BHr[2][4], BLr[2][4];
#pragma unroll
    for (int ks = 0; ks < 2; ++ks)
#pragma unroll
        for (int nt = 0; nt < 4; ++nt) {
            BHr[ks][nt] = bh[(ks * 4 + nt) * 64 + lane];
            BLr[ks][nt] = bl[(ks * 4 + nt) * 64 + lane];
        }
    f32x4 acc0 = {0.f, 0.f, 0.f, 0.f}, acc1 = acc0, acc2 = acc0, acc3 = acc0;
#pragma unroll
    for (int ks = 0; ks < 2; ++ks) {
        MAKE_A(ks)
        acc0 = __builtin_amdgcn_mfma_f32_16x16x32_f16(ah, BHr[ks][0], acc0, 0, 0, 0);
        acc1 = __builtin_amdgcn_mfma_f32_16x16x32_f16(ah, BHr[ks][1], acc1, 0, 0, 0);
        acc2 = __builtin_amdgcn_mfma_f32_16x16x32_f16(ah, BHr[ks][2], acc2, 0, 0, 0);
        acc3 = __builtin_amdgcn_mfma_f32_16x16x32_f16(ah, BHr[ks][3], acc3, 0, 0, 0);
        acc0 = __builtin_amdgcn_mfma_f32_16x16x32_f16(ah, BLr[ks][0], acc0, 0, 0, 0);
        acc1 = __builtin_amdgcn_mfma_f32_16x16x32_f16(ah, BLr[ks][1], acc1, 0, 0, 0);
        acc2 = __builtin_amdgcn_mfma_f32_16x16x32_f16(ah, BLr[ks][2], acc2, 0, 0, 0);
        acc3 = __builtin_amdgcn_mfma_f32_16x16x32_f16(ah, BLr[ks][3], acc3, 0, 0, 0);
        acc0 = __builtin_amdgcn_mfma_f32_16x16x32_f16(al, BHr[ks][0], acc0, 0, 0, 0);
        acc1 = __builtin_amdgcn_mfma_f32_16x16x32_f16(al, BHr[ks][1], acc1, 0, 0, 0);
        acc2 = __builtin_amdgcn_mfma_f32_16x16x32_f16(al, BHr[ks][2], acc2, 0, 0, 0);
        acc3 = __builtin_amdgcn_mfma_f32_16x16x32_f16(al, BHr[ks][3], acc3, 0, 0, 0);
    }
    __syncthreads();
#pragma unroll
    for (int r = 0; r < 4; ++r) {
        int row = 4 * kg + r;
        xw[row * 68 + mrow]      = acc0[r];
        xw[row * 68 + 16 + mrow] = acc1[r];
        xw[row * 68 + 32 + mrow] = acc2[r];
        xw[row * 68 + 48 + mrow] = acc3[r];
    }
    __syncthreads();

    float ps = 0.f, pd = 0.f;
#pragma unroll
    for (int j = 0; j < 16; ++j) {
        int f = kg * 16 + j;
        float v = xw[mrow * 68 + f];
        ps += v * a_s[f];
        pd += v * a_d[f];
    }
    ps += __shfl_xor(ps, 16);
    pd += __shfl_xor(pd, 16);
    float psB = __shfl_xor(ps, 32);
    float pdB = __shfl_xor(pd, 32);
    if (kg == 0 && n < NN) {
        es2v[n] = make_float2(ps, psB);
        ed2v[n] = make_float2(pd, pdB);
    }

#pragma unroll
    for (int i = 0; i < 8; ++i) {
        int idx = lane + 64 * i;
        int nl = idx >> 5;
        int c = idx & 31;
        int g = nodeBase + nl;
        if (g < NN) {
            __half2 hv = __floats2half2_rn(xw[nl * 68 + 2 * c], xw[nl * 68 + 2 * c + 1]);
            *reinterpret_cast<__half2*>(&xph[(size_t)g * 64 + 2 * c]) = hv;
        }
    }
}

// ---------------- layer-2 GAT: OCT edges, fp16 in/out, nontemporal streams ----------------
__global__ void __launch_bounds__(256) k_gat2(
    const __half* __restrict__ xph, const float2* __restrict__ es2v,
    const float2* __restrict__ ed2v,
    const int* __restrict__ rowptr, const unsigned* __restrict__ srcl,
    const float* __restrict__ bias, __half* __restrict__ yh) {
    int wid = (blockIdx.x * blockDim.x + threadIdx.x) >> 6;
    int lane = threadIdx.x & 63;
    if (wid >= NN) return;
    int g = lane >> 3;            // edge slot within octet (0..7)
    int t = lane & 7;             // channel octet index: channels 8t..8t+7
    bool hh = t >= 4;             // head 1 for channels >= 32
    int ch = 8 * t;
    float2 edp = ed2v[wid];
    float edv = hh ? edp.y : edp.x;
    int beg = rowptr[wid], end = rowptr[wid + 1];
    float sum = 0.f;
    float a0 = 0.f, a1 = 0.f, a2 = 0.f, a3 = 0.f;
    float a4 = 0.f, a5 = 0.f, a6 = 0.f, a7 = 0.f;
    int k = beg;

#define GO(kk)                                                                    \
    {                                                                             \
        int s_ = (int)(__builtin_nontemporal_load(&srcl[(kk) + g]) & SMASK);      \
        float2 ep_ = es2v[s_];                                                    \
        u32x4 xr_ = *reinterpret_cast<const u32x4*>(&xph[(size_t)s_ * 64 + ch]);  \
        float e_ = (hh ? ep_.y : ep_.x) + edv;                                    \
        e_ = fmaxf(e_, NEG * e_);                                                 \
        float w_ = __expf(e_);                                                    \
        unsigned q0_ = xr_.x, q1_ = xr_.y, q2_ = xr_.z, q3_ = xr_.w;              \
        float2 p0_ = __half22float2(*reinterpret_cast<const __half2*>(&q0_));     \
        float2 p1_ = __half22float2(*reinterpret_cast<const __half2*>(&q1_));     \
        float2 p2_ = __half22float2(*reinterpret_cast<const __half2*>(&q2_));     \
        float2 p3_ = __half22float2(*reinterpret_cast<const __half2*>(&q3_));     \
        sum += w_;                                                                \
        a0 += w_ * p0_.x; a1 += w_ * p0_.y; a2 += w_ * p1_.x; a3 += w_ * p1_.y;   \
        a4 += w_ * p2_.x; a5 += w_ * p2_.y; a6 += w_ * p3_.x; a7 += w_ * p3_.y;   \
    }

    for (; k + 16 <= end; k += 16) {
        GO(k) GO(k + 8)
    }
    for (; k + 8 <= end; k += 8) {
        GO(k)
    }
    if (k < end) {                 // masked tail (1..7 edges)
        int idx = k + g;
        bool valid = idx < end;
        int s_ = (int)(srcl[valid ? idx : k] & SMASK);
        float2 ep_ = es2v[s_];
        u32x4 xr_ = *reinterpret_cast<const u32x4*>(&xph[(size_t)s_ * 64 + ch]);
        float e_ = (hh ? ep_.y : ep_.x) + edv;
        e_ = fmaxf(e_, NEG * e_);
        float w_ = valid ? __expf(e_) : 0.f;
        unsigned q0_ = xr_.x, q1_ = xr_.y, q2_ = xr_.z, q3_ = xr_.w;
        float2 p0_ = __half22float2(*reinterpret_cast<const __half2*>(&q0_));
        float2 p1_ = __half22float2(*reinterpret_cast<const __half2*>(&q1_));
        float2 p2_ = __half22float2(*reinterpret_cast<const __half2*>(&q2_));
        float2 p3_ = __half22float2(*reinterpret_cast<const __half2*>(&q3_));
        sum += w_;
        a0 += w_ * p0_.x; a1 += w_ * p0_.y; a2 += w_ * p1_.x; a3 += w_ * p1_.y;
        a4 += w_ * p2_.x; a5 += w_ * p2_.y; a6 += w_ * p3_.x; a7 += w_ * p3_.y;
    }
#undef GO

#pragma unroll
    for (int off = 8; off <= 32; off <<= 1) {
        sum += __shfl_xor(sum, off);
        a0 += __shfl_xor(a0, off); a1 += __shfl_xor(a1, off);
        a2 += __shfl_xor(a2, off); a3 += __shfl_xor(a3, off);
        a4 += __shfl_xor(a4, off); a5 += __shfl_xor(a5, off);
        a6 += __shfl_xor(a6, off); a7 += __shfl_xor(a7, off);
    }
    if (lane < 8) {
        float rs = 1.f / (sum + 1e-16f);
        __half2 o0 = __floats2half2_rn(fmaxf(a0 * rs + bias[ch], 0.f),
                                       fmaxf(a1 * rs + bias[ch + 1], 0.f));
        __half2 o1 = __floats2half2_rn(fmaxf(a2 * rs + bias[ch + 2], 0.f),
                                       fmaxf(a3 * rs + bias[ch + 3], 0.f));
        __half2 o2 = __floats2half2_rn(fmaxf(a4 * rs + bias[ch + 4], 0.f),
                                       fmaxf(a5 * rs + bias[ch + 5], 0.f));
        __half2 o3 = __floats2half2_rn(fmaxf(a6 * rs + bias[ch + 6], 0.f),
                                       fmaxf(a7 * rs + bias[ch + 7], 0.f));
        u32x4 pk;
        pk.x = *reinterpret_cast<unsigned*>(&o0);
        pk.y = *reinterpret_cast<unsigned*>(&o1);
        pk.z = *reinterpret_cast<unsigned*>(&o2);
        pk.w = *reinterpret_cast<unsigned*>(&o3);
        __builtin_nontemporal_store(pk, reinterpret_cast<u32x4*>(&yh[(size_t)wid * 64 + ch]));
    }
}

// ---------------- fused MLP via MFMA (double-fp16 split), fp16 input ----------------
__global__ void __launch_bounds__(256) k_mlp(
    const __half* __restrict__ hin,
    const _Float16* __restrict__ BH, const _Float16* __restrict__ BL,
    const _Float16* __restrict__ BH5, const _Float16* __restrict__ BL5,
    const float* __restrict__ b1, const float* __restrict__ b2,
    const float* __restrict__ b3, const float* __restrict__ b4,
    const float* __restrict__ b5,
    float* __restrict__ out) {
    __shared__ float xs[4 * 16 * 68];
    int lane = threadIdx.x & 63;
    int w = threadIdx.x >> 6;
    float* xw = &xs[w * 1088];
    int nodeBase = blockIdx.x * 64 + w * 16;
    int mrow = lane & 15;
    int kg = lane >> 4;

#pragma unroll
    for (int i = 0; i < 2; ++i) {
        int idx = lane + 64 * i;       // 0..127 (16 nodes x 8 octets)
        int nl = idx >> 3;
        int c8 = (idx & 7) * 8;
        u32x4 t = {0u, 0u, 0u, 0u};
        if (nodeBase + nl < NN)
            t = __builtin_nontemporal_load(
                reinterpret_cast<const u32x4*>(&hin[(size_t)(nodeBase + nl) * 64 + c8]));
        unsigned q0 = t.x, q1 = t.y, q2 = t.z, q3 = t.w;
        float2 p0 = __half22float2(*reinterpret_cast<const __half2*>(&q0));
        float2 p1 = __half22float2(*reinterpret_cast<const __half2*>(&q1));
        float2 p2 = __half22float2(*reinterpret_cast<const __half2*>(&q2));
        float2 p3 = __half22float2(*reinterpret_cast<const __half2*>(&q3));
        f4 lo = make_float4(p0.x, p0.y, p1.x, p1.y);
        f4 hi = make_float4(p2.x, p2.y, p3.x, p3.y);
        *reinterpret_cast<f4*>(&xw[nl * 68 + c8]) = lo;
        *reinterpret_cast<f4*>(&xw[nl * 68 + c8 + 4]) = hi;
    }
    __syncthreads();

#define MLP_LAYER(L, Bp)                                                          \
    {                                                                             \
        const h8* bh = reinterpret_cast<const h8*>(BH + (L) * 4096);              \
        const h8* bl = reinterpret_cast<const h8*>(BL + (L) * 4096);              \
        h8 BHr[2][4], BLr[2][4];                                                  \
        _Pragma("unroll")                                                         \
        for (int ks = 0; ks < 2; ++ks)                                            \
            _Pragma("unroll")                                                     \
            for (int nt = 0; nt < 4; ++nt) {                                      \
                BHr[ks][nt] = bh[(ks * 4 + nt) * 64 + lane];                      \
                BLr[ks][nt] = bl[(ks * 4 + nt) * 64 + lane];                      \
            }                                                                     \
        float bj0 = Bp[mrow], bj1 = Bp[16 + mrow];                                \
        float bj2 = Bp[32 + mrow], bj3 = Bp[48 + mrow];                           \
        f32x4 acc0 = {0.f, 0.f, 0.f, 0.f}, acc1 = acc0, acc2 = acc0, acc3 = acc0; \
        _Pragma("unroll")                                                         \
        for (int ks = 0; ks < 2; ++ks) {                                          \
            MAKE_A(ks)                                                            \
            acc0 = __builtin_amdgcn_mfma_f32_16x16x32_f16(ah, BHr[ks][0], acc0, 0, 0, 0); \
            acc1 = __builtin_amdgcn_mfma_f32_16x16x32_f16(ah, BHr[ks][1], acc1, 0, 0, 0); \
            acc2 = __builtin_amdgcn_mfma_f32_16x16x32_f16(ah, BHr[ks][2], acc2, 0, 0, 0); \
            acc3 = __builtin_amdgcn_mfma_f32_16x16x32_f16(ah, BHr[ks][3], acc3, 0, 0, 0); \
            acc0 = __builtin_amdgcn_mfma_f32_16x16x32_f16(ah, BLr[ks][0], acc0, 0, 0, 0); \
            acc1 = __builtin_amdgcn_mfma_f32_16x16x32_f16(ah, BLr[ks][1], acc1, 0, 0, 0); \
            acc2 = __builtin_amdgcn_mfma_f32_16x16x32_f16(ah, BLr[ks][2], acc2, 0, 0, 0); \
            acc3 = __builtin_amdgcn_mfma_f32_16x16x32_f16(ah, BLr[ks][3], acc3, 0, 0, 0); \
            acc0 = __builtin_amdgcn_mfma_f32_16x16x32_f16(al, BHr[ks][0], acc0, 0, 0, 0); \
            acc1 = __builtin_amdgcn_mfma_f32_16x16x32_f16(al, BHr[ks][1], acc1, 0, 0, 0); \
            acc2 = __builtin_amdgcn_mfma_f32_16x16x32_f16(al, BHr[ks][2], acc2, 0, 0, 0); \
            acc3 = __builtin_amdgcn_mfma_f32_16x16x32_f16(al, BHr[ks][3], acc3, 0, 0, 0); \
        }                                                                         \
        __syncthreads();                                                          \
        _Pragma("unroll")                                                         \
        for (int r = 0; r < 4; ++r) {                                             \
            int row = 4 * kg + r;                                                 \
            xw[row * 68 + mrow]      = fmaxf(acc0[r] + bj0, 0.f);                 \
            xw[row * 68 + 16 + mrow] = fmaxf(acc1[r] + bj1, 0.f);                 \
            xw[row * 68 + 32 + mrow] = fmaxf(acc2[r] + bj2, 0.f);                 \
            xw[row * 68 + 48 + mrow] = fmaxf(acc3[r] + bj3, 0.f);                 \
        }                                                                         \
        __syncthreads();                                                          \
    }

    MLP_LAYER(0, b1)
    MLP_LAYER(1, b2)
    MLP_LAYER(2, b3)
    MLP_LAYER(3, b4)
#undef MLP_LAYER

    {
        const h8* bh = reinterpret_cast<const h8*>(BH5);
        const h8* bl = reinterpret_cast<const h8*>(BL5);
        f32x4 acc = {0.f, 0.f, 0.f, 0.f};
#pragma unroll
        for (int ks = 0; ks < 2; ++ks) {
            MAKE_A(ks)
            h8 b_h = bh[ks * 64 + lane];
            h8 b_l = bl[ks * 64 + lane];
            acc = __builtin_amdgcn_mfma_f32_16x16x32_f16(ah, b_h, acc, 0, 0, 0);
            acc = __builtin_amdgcn_mfma_f32_16x16x32_f16(ah, b_l, acc, 0, 0, 0);
            acc = __builtin_amdgcn_mfma_f32_16x16x32_f16(al, b_h, acc, 0, 0, 0);
        }
        if (mrow < 11) {
            float b5v = b5[mrow];
#pragma unroll
            for (int r = 0; r < 4; ++r) {
                int node = nodeBase + 4 * kg + r;
                if (node < NN) out[(size_t)node * 11 + mrow] = acc[r] + b5v;
            }
        }
    }
}

// ---------------- launch ----------------
extern "C" void kernel_launch(void* const* d_in, const int* in_sizes, int n_in,
                              void* d_out, int out_size, void* d_ws, size_t ws_size,
                              hipStream_t stream) {
    const float* h   = (const float*)d_in[0];
    const int*   ei  = (const int*)d_in[1];
    const float* gam = (const float*)d_in[2];
    const float* bet = (const float*)d_in[3];
    const float* W1  = (const float*)d_in[4];
    const float* as1 = (const float*)d_in[5];
    const float* ad1 = (const float*)d_in[6];
    const float* b1  = (const float*)d_in[7];
    const float* W2  = (const float*)d_in[8];
    const float* as2 = (const float*)d_in[9];
    const float* ad2 = (const float*)d_in[10];
    const float* b2  = (const float*)d_in[11];
    const float* fw1 = (const float*)d_in[12];
    const float* fb1 = (const float*)d_in[13];
    const float* fw2 = (const float*)d_in[14];
    const float* fb2 = (const float*)d_in[15];
    const float* fw3 = (const float*)d_in[16];
    const float* fb3 = (const float*)d_in[17];
    const float* fw4 = (const float*)d_in[18];
    const float* fb4 = (const float*)d_in[19];
    const float* fw5 = (const float*)d_in[20];
    const float* fb5 = (const float*)d_in[21];
    float* out = (float*)d_out;

    char* ws = (char*)d_ws;
    size_t off = 0;
    auto alloc = [&](size_t bytes) -> char* {
        char* p = ws + off;
        off += (bytes + 255) & ~(size_t)255;
        return p;
    };
    float* stats  = (float*)alloc(4 * sizeof(float));
    float* coef   = (float*)alloc(8 * sizeof(float));
    int*   gcnt   = (int*)alloc(NBUCK * sizeof(int));
    int*   rowptr = (int*)alloc((size_t)(NN + 1) * sizeof(int));
    unsigned* srcl = (unsigned*)alloc((size_t)ET * sizeof(unsigned));
    float2* es2v  = (float2*)alloc((size_t)NN * sizeof(float2));
    float2* ed2v  = (float2*)alloc((size_t)NN * sizeof(float2));
    _Float16* BH  = (_Float16*)alloc(5 * 4096 * sizeof(_Float16));
    _Float16* BL  = (_Float16*)alloc(5 * 4096 * sizeof(_Float16));
    _Float16* BH5 = (_Float16*)alloc(1024 * sizeof(_Float16));
    _Float16* BL5 = (_Float16*)alloc(1024 * sizeof(_Float16));
    float* bufA   = (float*)alloc((size_t)NN * 64 * sizeof(float));   // pairs -> xph
    float* bufB   = (float*)alloc((size_t)NN * 64 * sizeof(float));
    // aliases (dead before their hosts are written):
    unsigned* pairs = (unsigned*)bufA;                    // 196*10240 u32 = 8MB; dead after k_bucket
    __half* xph   = (__half*)bufA;
    f4*     agg1a = (f4*)bufB;                            // floats [0 .. 400000)
    float2* agg1s = (float2*)(bufB + 400000);             // [400000 .. 600000)
    f4*     nd1   = (f4*)(bufB + 600000);                 // [600000 .. 1000000)
    float2* ed1   = (float2*)(bufB + 1000000);            // [1000000 .. 1200000)
    __half* yh    = (__half*)bufB;                        // written by k_gat2 (after agg dead)
    (void)ws_size; (void)in_sizes; (void)n_in; (void)out_size;

    k_setup<<<96, 256, 0, stream>>>(stats, gcnt, W1, as1, ad1, coef,
                                    W2, fw1, fw2, fw3, fw4, fw5, BH, BL, BH5, BL5);
    k_bnstats<<<64, 256, 0, stream>>>(h, stats);

    // fused CSR build + layer-1 prep
    k_fpart<<<NBLK, 256, 0, stream>>>(ei, gcnt, pairs);
    k_bucket<<<NBUCK, 512, 0, stream>>>(pairs, gcnt, rowptr, srcl,
                                        h, stats, gam, bet, coef, nd1, ed1);

    // GAT layer 1 (rank-2 path, 8 lanes/dst)
    k_gat1<<<(NN * 8 + 255) / 256, 256, 0, stream>>>(nd1, ed1, rowptr, srcl, agg1a, agg1s);

    // layer-1 finalize + MFMA layer-2 transform (writes xph fp16, es2v, ed2v)
    k_xform2m<<<(NN + 63) / 64, 256, 0, stream>>>(agg1a, agg1s, W1, b1,
                                                  BH + 4 * 4096, BL + 4 * 4096,
                                                  as2, ad2, xph, es2v, ed2v);

    // GAT layer 2: oct-edge fp16 gather, fp16 output, nontemporal streams
    k_gat2<<<(NN * 64) / 256, 256, 0, stream>>>(xph, es2v, ed2v, rowptr, srcl, b2, yh);

    // MLP head: MFMA with double-fp16 split (fp16 input)
    k_mlp<<<(NN + 63) / 64, 256, 0, stream>>>(yh, BH, BL, BH5, BL5,
                                              fb1, fb2, fb3, fb4, fb5, out);
}

// Round 24
// 157.743 us; speedup vs baseline: 1.4819x; 1.4819x over previous
//
#include <hip/hip_runtime.h>
#include <hip/hip_fp16.h>
#include <math.h>

#define NN 100000
#define EE 1600000
#define ET (EE + NN)          // edges + self loops = 1,700,000
#define NEG 0.2f
#define SMASK 0x1FFFF

// CSR-build geometry: 196 buckets x 512 dst nodes
#define NBUCK 196
#define NBLK 416              // partition blocks
#define BITEMS 4096           // items per partition block (256 thr x 16)
#define BCAP 10240            // bucket capacity (mean 8676, sigma~93)

typedef float4 f4;
typedef _Float16 h8 __attribute__((ext_vector_type(8)));
typedef float f32x4 __attribute__((ext_vector_type(4)));
typedef unsigned u32x4 __attribute__((ext_vector_type(4)));   // native vec for nontemporal builtins

// ---------------- setup: stats=0, gcnt=0, coef + MFMA weight packing (fused) ----------------
__global__ void k_setup(float* stats, int* gcnt,
                        const float* __restrict__ W1, const float* __restrict__ as1,
                        const float* __restrict__ ad1, float* __restrict__ coef,
                        const float* __restrict__ W2g,
                        const float* __restrict__ w1, const float* __restrict__ w2,
                        const float* __restrict__ w3, const float* __restrict__ w4,
                        const float* __restrict__ w5,
                        _Float16* __restrict__ BH, _Float16* __restrict__ BL,
                        _Float16* __restrict__ BH5, _Float16* __restrict__ BL5) {
    int idx = blockIdx.x * blockDim.x + threadIdx.x;
    if (blockIdx.x == 0) {
        int i = threadIdx.x;
        if (i < 4) stats[i] = 0.f;
        if (i < NBUCK) gcnt[i] = 0;
        if (i >= 248) {                    // threads 248..255 compute coef[0..7]
            int t = i - 248;
            int sd = t >> 2, hh = (t >> 1) & 1, c0 = t & 1;
            const float* a = sd ? ad1 : as1;
            float s = 0.f;
            for (int c = 0; c < 32; ++c) s += W1[(hh * 32 + c) * 2 + c0] * a[hh * 32 + c];
            coef[t] = s;
        }
    }
    if (idx < 5 * 4096) {
        int L = idx >> 12;
        int r = idx & 4095;
        int ks = r >> 11, nt = (r >> 9) & 3, lane = (r >> 3) & 63, j = r & 7;
        const float* W = (L == 0) ? w1 : (L == 1) ? w2 : (L == 2) ? w3 : (L == 3) ? w4 : W2g;
        int n = nt * 16 + (lane & 15);
        int k = ks * 32 + 8 * (lane >> 4) + j;
        float v = W[n * 64 + k];
        _Float16 hi = (_Float16)v;
        BH[idx] = hi;
        BL[idx] = (_Float16)(v - (float)hi);
    }
    if (idx < 1024) {
        int ks = idx >> 9, lane = (idx >> 3) & 63, j = idx & 7;
        int n = lane & 15;
        int k = ks * 32 + 8 * (lane >> 4) + j;
        float v = (n < 11) ? w5[n * 64 + k] : 0.f;
        _Float16 hi = (_Float16)v;
        BH5[idx] = hi;
        BL5[idx] = (_Float16)(v - (float)hi);
    }
}

// ---------------- BN statistics: block-level reduce, 4 atomics/block (64 blocks) ----------------
__global__ void k_bnstats(const float* __restrict__ h, float* stats) {
    __shared__ float red[16];
    int gid = blockIdx.x * blockDim.x + threadIdx.x;
    int stride = gridDim.x * blockDim.x;
    float s0 = 0.f, s1 = 0.f, q0 = 0.f, q1 = 0.f;
    for (int i = gid; i < NN; i += stride) {
        float2 v = reinterpret_cast<const float2*>(h)[i];
        s0 += v.x; q0 += v.x * v.x;
        s1 += v.y; q1 += v.y * v.y;
    }
#pragma unroll
    for (int off = 32; off >= 1; off >>= 1) {
        s0 += __shfl_xor(s0, off);
        s1 += __shfl_xor(s1, off);
        q0 += __shfl_xor(q0, off);
        q1 += __shfl_xor(q1, off);
    }
    int wv = threadIdx.x >> 6;
    if ((threadIdx.x & 63) == 0) {
        red[wv * 4 + 0] = s0; red[wv * 4 + 1] = s1;
        red[wv * 4 + 2] = q0; red[wv * 4 + 3] = q1;
    }
    __syncthreads();
    if (threadIdx.x == 0) {
        float t0 = 0.f, t1 = 0.f, t2 = 0.f, t3 = 0.f;
#pragma unroll
        for (int i = 0; i < 4; ++i) {
            t0 += red[i * 4 + 0]; t1 += red[i * 4 + 1];
            t2 += red[i * 4 + 2]; t3 += red[i * 4 + 3];
        }
        atomicAdd(&stats[0], t0); atomicAdd(&stats[1], t1);
        atomicAdd(&stats[2], t2); atomicAdd(&stats[3], t3);
    }
}

// ---------------- fused CSR partition (NT loads only; scattered stores stay cached) ----------------
__global__ void __launch_bounds__(256) k_fpart(const int* __restrict__ ei, int* gcnt,
                                               unsigned* __restrict__ pairs) {
    __shared__ int hist[NBUCK];
    __shared__ int cur[NBUCK];
    int tid = threadIdx.x, blk = blockIdx.x;
    if (tid < NBUCK) hist[tid] = 0;
    int ss[16], dd[16];
    int base = blk * BITEMS;
    __syncthreads();
#pragma unroll
    for (int it = 0; it < 16; ++it) {
        int i = base + it * 256 + tid;
        int s = 0, d = -1;
        if (i < ET) {
            if (i < EE) {
                s = __builtin_nontemporal_load(&ei[i]);
                d = __builtin_nontemporal_load(&ei[EE + i]);
            } else { s = d = i - EE; }
            atomicAdd(&hist[d >> 9], 1);
        }
        ss[it] = s; dd[it] = d;
    }
    __syncthreads();
    if (tid < NBUCK) cur[tid] = tid * BCAP + atomicAdd(&gcnt[tid], hist[tid]);
    __syncthreads();
#pragma unroll
    for (int it = 0; it < 16; ++it) {
        int d = dd[it];
        if (d >= 0) {
            int pos = atomicAdd(&cur[d >> 9], 1);
            pairs[pos] = (unsigned)ss[it] | ((unsigned)(d & 511) << 17);   // cached: L2 coalesces scatter
        }
    }
}

// ---------------- per-bucket local CSR + fused layer-1 prep ----------------
__global__ void __launch_bounds__(512) k_bucket(const unsigned* __restrict__ pairs,
                                                 const int* __restrict__ gcnt,
                                                 int* __restrict__ rowptr,
                                                 unsigned* __restrict__ srcl,
                                                 const float* __restrict__ h,
                                                 const float* __restrict__ stats,
                                                 const float* __restrict__ gamma,
                                                 const float* __restrict__ beta,
                                                 const float* __restrict__ coef,
                                                 f4* __restrict__ nd1, float2* __restrict__ ed1) {
    __shared__ int sh[512];
    __shared__ int se[512];
    int b = blockIdx.x, tid = threadIdx.x;
    sh[tid] = (tid < b) ? gcnt[tid] : 0;
    __syncthreads();
    for (int off = 256; off >= 1; off >>= 1) {
        if (tid < off) sh[tid] += sh[tid + off];
        __syncthreads();
    }
    int obase = sh[0];
    __syncthreads();
    int cnt = gcnt[b];
    int ibase = b * BCAP;
    sh[tid] = 0;
    __syncthreads();
    for (int k = tid; k < cnt; k += 512) atomicAdd(&sh[pairs[ibase + k] >> 17], 1);
    __syncthreads();
    int deg = sh[tid];
    se[tid] = deg;
    __syncthreads();
    for (int off = 1; off < 512; off <<= 1) {
        int t = (tid >= off) ? se[tid - off] : 0;
        __syncthreads();
        se[tid] += t;
        __syncthreads();
    }
    int excl = se[tid] - deg;
    int node = (b << 9) + tid;
    if (node < NN) rowptr[node] = obase + excl;
    sh[tid] = obase + excl;     // cursor
    __syncthreads();
    for (int k = tid; k < cnt; k += 512) {
        unsigned p = pairs[ibase + k];
        int pos = atomicAdd(&sh[p >> 17], 1);
        srcl[pos] = p;          // cached: L2 coalesces scatter (NT here = 13x write amplification)
    }
    if (b == 0 && tid == 0) rowptr[NN] = ET;

    // fused layer-1 prep
    if (node < NN) {
        const float inv = 1.f / (float)NN;
        float mu0 = stats[0] * inv, mu1 = stats[1] * inv;
        float v0 = stats[2] * inv - mu0 * mu0;
        float v1 = stats[3] * inv - mu1 * mu1;
        float g0 = rsqrtf(v0 + 1e-5f) * gamma[0];
        float g1 = rsqrtf(v1 + 1e-5f) * gamma[1];
        float2 hv = reinterpret_cast<const float2*>(h)[node];
        float x0 = (hv.x - mu0) * g0 + beta[0];
        float x1 = (hv.y - mu1) * g1 + beta[1];
        nd1[node] = make_float4(x0 * coef[0] + x1 * coef[1], x0 * coef[2] + x1 * coef[3], x0, x1);
        ed1[node] = make_float2(x0 * coef[4] + x1 * coef[5], x0 * coef[6] + x1 * coef[7]);
    }
}

// ---------------- layer-1 GAT: 8 lanes per dst, shfl reduce (NT srcl loads) ----------------
__global__ void __launch_bounds__(256) k_gat1(
    const f4* __restrict__ nd1, const float2* __restrict__ ed1,
    const int* __restrict__ rowptr, const unsigned* __restrict__ srcl,
    f4* __restrict__ agg1a, float2* __restrict__ agg1s) {
    int gid = blockIdx.x * blockDim.x + threadIdx.x;
    int n = gid >> 3;
    int sub = gid & 7;
    if (n >= NN) return;
    int beg = rowptr[n], end = rowptr[n + 1];
    float2 ed = ed1[n];
    float A0 = 0.f, B0 = 0.f, S0 = 0.f, A1 = 0.f, B1 = 0.f, S1 = 0.f;
    for (int k = beg + sub; k < end; k += 8) {
        int s = (int)(__builtin_nontemporal_load(&srcl[k]) & SMASK);
        f4 p = nd1[s];
        float e0 = p.x + ed.x;
        float e1 = p.y + ed.y;
        e0 = fmaxf(e0, NEG * e0);
        e1 = fmaxf(e1, NEG * e1);
        float w0 = __expf(e0);
        float w1 = __expf(e1);
        A0 += w0 * p.z; B0 += w0 * p.w; S0 += w0;
        A1 += w1 * p.z; B1 += w1 * p.w; S1 += w1;
    }
#pragma unroll
    for (int off = 1; off < 8; off <<= 1) {
        A0 += __shfl_xor(A0, off);
        B0 += __shfl_xor(B0, off);
        S0 += __shfl_xor(S0, off);
        A1 += __shfl_xor(A1, off);
        B1 += __shfl_xor(B1, off);
        S1 += __shfl_xor(S1, off);
    }
    if (sub == 0) {
        agg1a[n] = make_float4(A0, B0, A1, B1);
        agg1s[n] = make_float2(S0, S1);
    }
}

#define MAKE_A(ks)                                                                \
    f4 a0 = *reinterpret_cast<const f4*>(&xw[mrow * 68 + kg * 8 + (ks) * 32]);    \
    f4 a1 = *reinterpret_cast<const f4*>(&xw[mrow * 68 + kg * 8 + (ks) * 32 + 4]);\
    float av0 = a0.x, av1 = a0.y, av2 = a0.z, av3 = a0.w;                         \
    float av4 = a1.x, av5 = a1.y, av6 = a1.z, av7 = a1.w;                         \
    h8 ah, al;                                                                    \
    { _Float16 t;                                                                 \
      t = (_Float16)av0; ah[0] = t; al[0] = (_Float16)(av0 - (float)t);           \
      t = (_Float16)av1; ah[1] = t; al[1] = (_Float16)(av1 - (float)t);           \
      t = (_Float16)av2; ah[2] = t; al[2] = (_Float16)(av2 - (float)t);           \
      t = (_Float16)av3; ah[3] = t; al[3] = (_Float16)(av3 - (float)t);           \
      t = (_Float16)av4; ah[4] = t; al[4] = (_Float16)(av4 - (float)t);           \
      t = (_Float16)av5; ah[5] = t; al[5] = (_Float16)(av5 - (float)t);           \
      t = (_Float16)av6; ah[6] = t; al[6] = (_Float16)(av6 - (float)t);           \
      t = (_Float16)av7; ah[7] = t; al[7] = (_Float16)(av7 - (float)t); }

// ---------------- layer-1 finalize + MFMA linear(64->64) + layer-2 attn scalars ----------------
__global__ void __launch_bounds__(256) k_xform2m(
    const f4* __restrict__ agg1a, const float2* __restrict__ agg1s,
    const float* __restrict__ W1, const float* __restrict__ b1,
    const _Float16* __restrict__ BH2, const _Float16* __restrict__ BL2,
    const float* __restrict__ a_s, const float* __restrict__ a_d,
    __half* __restrict__ xph, float2* __restrict__ es2v, float2* __restrict__ ed2v) {
    __shared__ float xs[4 * 1088];
    int lane = threadIdx.x & 63;
    int w = threadIdx.x >> 6;
    float* xw = &xs[w * 1088];
    int nodeBase = blockIdx.x * 64 + w * 16;
    int mrow = lane & 15;
    int kg = lane >> 4;
    int n = nodeBase + mrow;

    f4 ag = make_float4(0.f, 0.f, 0.f, 0.f);
    float2 sg = make_float2(1.f, 1.f);
    if (n < NN) { ag = agg1a[n]; sg = agg1s[n]; }
    float r0 = 1.f / (sg.x + 1e-16f);
    float r1 = 1.f / (sg.y + 1e-16f);
#pragma unroll
    for (int j = 0; j < 16; ++j) {
        int f = kg * 16 + j;
        float A = (f < 32) ? ag.x : ag.z;
        float B = (f < 32) ? ag.y : ag.w;
        float r = (f < 32) ? r0 : r1;
        xw[mrow * 68 + f] = fmaxf((A * W1[2 * f] + B * W1[2 * f + 1]) * r + b1[f], 0.f);
    }
    __syncthreads();

    const h8* bh = reinterpret_cast<const h8*>(BH2);
    const h8* bl = reinterpret_cast<const h8*>(BL2);
    h8 BHr[2][4], BLr[2][4];
#pragma unroll
    for (int ks = 0; ks < 2; ++ks)
#pragma unroll
        for (int nt = 0; nt < 4; ++nt) {
            BHr[ks][nt] = bh[(ks * 4 + nt) * 64 + lane];
            BLr[ks][nt] = bl[(ks * 4 + nt) * 64 + lane];
        }
    f32x4 acc0 = {0.f, 0.f, 0.f, 0.f}, acc1 = acc0, acc2 = acc0, acc3 = acc0;
#pragma unroll
    for (int ks = 0; ks < 2; ++ks) {
        MAKE_A(ks)
        acc0 = __builtin_amdgcn_mfma_f32_16x16x32_f16(ah, BHr[ks][0], acc0, 0, 0, 0);
        acc1 = __builtin_amdgcn_mfma_f32_16x16x32_f16(ah, BHr[ks][1], acc1, 0, 0, 0);
        acc2 = __builtin_amdgcn_mfma_f32_16x16x32_f16(ah, BHr[ks][2], acc2, 0, 0, 0);
        acc3 = __builtin_amdgcn_mfma_f32_16x16x32_f16(ah, BHr[ks][3], acc3, 0, 0, 0);
        acc0 = __builtin_amdgcn_mfma_f32_16x16x32_f16(ah, BLr[ks][0], acc0, 0, 0, 0);
        acc1 = __builtin_amdgcn_mfma_f32_16x16x32_f16(ah, BLr[ks][1], acc1, 0, 0, 0);
        acc2 = __builtin_amdgcn_mfma_f32_16x16x32_f16(ah, BLr[ks][2], acc2, 0, 0, 0);
        acc3 = __builtin_amdgcn_mfma_f32_16x16x32_f16(ah, BLr[ks][3], acc3, 0, 0, 0);
        acc0 = __builtin_amdgcn_mfma_f32_16x16x32_f16(al, BHr[ks][0], acc0, 0, 0, 0);
        acc1 = __builtin_amdgcn_mfma_f32_16x16x32_f16(al, BHr[ks][1], acc1, 0, 0, 0);
        acc2 = __builtin_amdgcn_mfma_f32_16x16x32_f16(al, BHr[ks][2], acc2, 0, 0, 0);
        acc3 = __builtin_amdgcn_mfma_f32_16x16x32_f16(al, BHr[ks][3], acc3, 0, 0, 0);
    }
    __syncthreads();
#pragma unroll
    for (int r = 0; r < 4; ++r) {
        int row = 4 * kg + r;
        xw[row * 68 + mrow]      = acc0[r];
        xw[row * 68 + 16 + mrow] = acc1[r];
        xw[row * 68 + 32 + mrow] = acc2[r];
        xw[row * 68 + 48 + mrow] = acc3[r];
    }
    __syncthreads();

    float ps = 0.f, pd = 0.f;
#pragma unroll
    for (int j = 0; j < 16; ++j) {
        int f = kg * 16 + j;
        float v = xw[mrow * 68 + f];
        ps += v * a_s[f];
        pd += v * a_d[f];
    }
    ps += __shfl_xor(ps, 16);
    pd += __shfl_xor(pd, 16);
    float psB = __shfl_xor(ps, 32);
    float pdB = __shfl_xor(pd, 32);
    if (kg == 0 && n < NN) {
        es2v[n] = make_float2(ps, psB);
        ed2v[n] = make_float2(pd, pdB);
    }

#pragma unroll
    for (int i = 0; i < 8; ++i) {
        int idx = lane + 64 * i;
        int nl = idx >> 5;
        int c = idx & 31;
        int g = nodeBase + nl;
        if (g < NN) {
            __half2 hv = __floats2half2_rn(xw[nl * 68 + 2 * c], xw[nl * 68 + 2 * c + 1]);
            *reinterpret_cast<__half2*>(&xph[(size_t)g * 64 + 2 * c]) = hv;
        }
    }
}

// ---------------- layer-2 GAT: OCT edges, fp16 in/out, NT srcl loads + NT yh store ----------------
__global__ void __launch_bounds__(256) k_gat2(
    const __half* __restrict__ xph, const float2* __restrict__ es2v,
    const float2* __restrict__ ed2v,
    const int* __restrict__ rowptr, const unsigned* __restrict__ srcl,
    const float* __restrict__ bias, __half* __restrict__ yh) {
    int wid = (blockIdx.x * blockDim.x + threadIdx.x) >> 6;
    int lane = threadIdx.x & 63;
    if (wid >= NN) return;
    int g = lane >> 3;            // edge slot within octet (0..7)
    int t = lane & 7;             // channel octet index: channels 8t..8t+7
    bool hh = t >= 4;             // head 1 for channels >= 32
    int ch = 8 * t;
    float2 edp = ed2v[wid];
    float edv = hh ? edp.y : edp.x;
    int beg = rowptr[wid], end = rowptr[wid + 1];
    float sum = 0.f;
    float a0 = 0.f, a1 = 0.f, a2 = 0.f, a3 = 0.f;
    float a4 = 0.f, a5 = 0.f, a6 = 0.f, a7 = 0.f;
    int k = beg;

#define GO(kk)                                                                    \
    {                                                                             \
        int s_ = (int)(__builtin_nontemporal_load(&srcl[(kk) + g]) & SMASK);      \
        float2 ep_ = es2v[s_];                                                    \
        u32x4 xr_ = *reinterpret_cast<const u32x4*>(&xph[(size_t)s_ * 64 + ch]);  \
        float e_ = (hh ? ep_.y : ep_.x) + edv;                                    \
        e_ = fmaxf(e_, NEG * e_);                                                 \
        float w_ = __expf(e_);                                                    \
        unsigned q0_ = xr_.x, q1_ = xr_.y, q2_ = xr_.z, q3_ = xr_.w;              \
        float2 p0_ = __half22float2(*reinterpret_cast<const __half2*>(&q0_));     \
        float2 p1_ = __half22float2(*reinterpret_cast<const __half2*>(&q1_));     \
        float2 p2_ = __half22float2(*reinterpret_cast<const __half2*>(&q2_));     \
        float2 p3_ = __half22float2(*reinterpret_cast<const __half2*>(&q3_));     \
        sum += w_;                                                                \
        a0 += w_ * p0_.x; a1 += w_ * p0_.y; a2 += w_ * p1_.x; a3 += w_ * p1_.y;   \
        a4 += w_ * p2_.x; a5 += w_ * p2_.y; a6 += w_ * p3_.x; a7 += w_ * p3_.y;   \
    }

    for (; k + 16 <= end; k += 16) {
        GO(k) GO(k + 8)
    }
    for (; k + 8 <= end; k += 8) {
        GO(k)
    }
    if (k < end) {                 // masked tail (1..7 edges)
        int idx = k + g;
        bool valid = idx < end;
        int s_ = (int)(srcl[valid ? idx : k] & SMASK);
        float2 ep_ = es2v[s_];
        u32x4 xr_ = *reinterpret_cast<const u32x4*>(&xph[(size_t)s_ * 64 + ch]);
        float e_ = (hh ? ep_.y : ep_.x) + edv;
        e_ = fmaxf(e_, NEG * e_);
        float w_ = valid ? __expf(e_) : 0.f;
        unsigned q0_ = xr_.x, q1_ = xr_.y, q2_ = xr_.z, q3_ = xr_.w;
        float2 p0_ = __half22float2(*reinterpret_cast<const __half2*>(&q0_));
        float2 p1_ = __half22float2(*reinterpret_cast<const __half2*>(&q1_));
        float2 p2_ = __half22float2(*reinterpret_cast<const __half2*>(&q2_));
        float2 p3_ = __half22float2(*reinterpret_cast<const __half2*>(&q3_));
        sum += w_;
        a0 += w_ * p0_.x; a1 += w_ * p0_.y; a2 += w_ * p1_.x; a3 += w_ * p1_.y;
        a4 += w_ * p2_.x; a5 += w_ * p2_.y; a6 += w_ * p3_.x; a7 += w_ * p3_.y;
    }
#undef GO

#pragma unroll
    for (int off = 8; off <= 32; off <<= 1) {
        sum += __shfl_xor(sum, off);
        a0 += __shfl_xor(a0, off); a1 += __shfl_xor(a1, off);
        a2 += __shfl_xor(a2, off); a3 += __shfl_xor(a3, off);
        a4 += __shfl_xor(a4, off); a5 += __shfl_xor(a5, off);
        a6 += __shfl_xor(a6, off); a7 += __shfl_xor(a7, off);
    }
    if (lane < 8) {
        float rs = 1.f / (sum + 1e-16f);
        __half2 o0 = __floats2half2_rn(fmaxf(a0 * rs + bias[ch], 0.f),
                                       fmaxf(a1 * rs + bias[ch + 1], 0.f));
        __half2 o1 = __floats2half2_rn(fmaxf(a2 * rs + bias[ch + 2], 0.f),
                                       fmaxf(a3 * rs + bias[ch + 3], 0.f));
        __half2 o2 = __floats2half2_rn(fmaxf(a4 * rs + bias[ch + 4], 0.f),
                                       fmaxf(a5 * rs + bias[ch + 5], 0.f));
        __half2 o3 = __floats2half2_rn(fmaxf(a6 * rs + bias[ch + 6], 0.f),
                                       fmaxf(a7 * rs + bias[ch + 7], 0.f));
        u32x4 pk;
        pk.x = *reinterpret_cast<unsigned*>(&o0);
        pk.y = *reinterpret_cast<unsigned*>(&o1);
        pk.z = *reinterpret_cast<unsigned*>(&o2);
        pk.w = *reinterpret_cast<unsigned*>(&o3);
        __builtin_nontemporal_store(pk, reinterpret_cast<u32x4*>(&yh[(size_t)wid * 64 + ch]));
    }
}

// ---------------- fused MLP via MFMA (double-fp16 split), fp16 input ----------------
__global__ void __launch_bounds__(256) k_mlp(
    const __half* __restrict__ hin,
    const _Float16* __restrict__ BH, const _Float16* __restrict__ BL,
    const _Float16* __restrict__ BH5, const _Float16* __restrict__ BL5,
    const float* __restrict__ b1, const float* __restrict__ b2,
    const float* __restrict__ b3, const float* __restrict__ b4,
    const float* __restrict__ b5,
    float* __restrict__ out) {
    __shared__ float xs[4 * 16 * 68];
    int lane = threadIdx.x & 63;
    int w = threadIdx.x >> 6;
    float* xw = &xs[w * 1088];
    int nodeBase = blockIdx.x * 64 + w * 16;
    int mrow = lane & 15;
    int kg = lane >> 4;

#pragma unroll
    for (int i = 0; i < 2; ++i) {
        int idx = lane + 64 * i;       // 0..127 (16 nodes x 8 octets)
        int nl = idx >> 3;
        int c8 = (idx & 7) * 8;
        u32x4 t = {0u, 0u, 0u, 0u};
        if (nodeBase + nl < NN)
            t = __builtin_nontemporal_load(
                reinterpret_cast<const u32x4*>(&hin[(size_t)(nodeBase + nl) * 64 + c8]));
        unsigned q0 = t.x, q1 = t.y, q2 = t.z, q3 = t.w;
        float2 p0 = __half22float2(*reinterpret_cast<const __half2*>(&q0));
        float2 p1 = __half22float2(*reinterpret_cast<const __half2*>(&q1));
        float2 p2 = __half22float2(*reinterpret_cast<const __half2*>(&q2));
        float2 p3 = __half22float2(*reinterpret_cast<const __half2*>(&q3));
        f4 lo = make_float4(p0.x, p0.y, p1.x, p1.y);
        f4 hi = make_float4(p2.x, p2.y, p3.x, p3.y);
        *reinterpret_cast<f4*>(&xw[nl * 68 + c8]) = lo;
        *reinterpret_cast<f4*>(&xw[nl * 68 + c8 + 4]) = hi;
    }
    __syncthreads();

#define MLP_LAYER(L, Bp)                                                          \
    {                                                                             \
        const h8* bh = reinterpret_cast<const h8*>(BH + (L) * 4096);              \
        const h8* bl = reinterpret_cast<const h8*>(BL + (L) * 4096);              \
        h8 BHr[2][4], BLr[2][4];                                                  \
        _Pragma("unroll")                                                         \
        for (int ks = 0; ks < 2; ++ks)                                            \
            _Pragma("unroll")                                                     \
            for (int nt = 0; nt < 4; ++nt) {                                      \
                BHr[ks][nt] = bh[(ks * 4 + nt) * 64 + lane];                      \
                BLr[ks][nt] = bl[(ks * 4 + nt) * 64 + lane];                      \
            }                                                                     \
        float bj0 = Bp[mrow], bj1 = Bp[16 + mrow];                                \
        float bj2 = Bp[32 + mrow], bj3 = Bp[48 + mrow];                           \
        f32x4 acc0 = {0.f, 0.f, 0.f, 0.f}, acc1 = acc0, acc2 = acc0, acc3 = acc0; \
        _Pragma("unroll")                                                         \
        for (int ks = 0; ks < 2; ++ks) {                                          \
            MAKE_A(ks)                                                            \
            acc0 = __builtin_amdgcn_mfma_f32_16x16x32_f16(ah, BHr[ks][0], acc0, 0, 0, 0); \
            acc1 = __builtin_amdgcn_mfma_f32_16x16x32_f16(ah, BHr[ks][1], acc1, 0, 0, 0); \
            acc2 = __builtin_amdgcn_mfma_f32_16x16x32_f16(ah, BHr[ks][2], acc2, 0, 0, 0); \
            acc3 = __builtin_amdgcn_mfma_f32_16x16x32_f16(ah, BHr[ks][3], acc3, 0, 0, 0); \
            acc0 = __builtin_amdgcn_mfma_f32_16x16x32_f16(ah, BLr[ks][0], acc0, 0, 0, 0); \
            acc1 = __builtin_amdgcn_mfma_f32_16x16x32_f16(ah, BLr[ks][1], acc1, 0, 0, 0); \
            acc2 = __builtin_amdgcn_mfma_f32_16x16x32_f16(ah, BLr[ks][2], acc2, 0, 0, 0); \
            acc3 = __builtin_amdgcn_mfma_f32_16x16x32_f16(ah, BLr[ks][3], acc3, 0, 0, 0); \
            acc0 = __builtin_amdgcn_mfma_f32_16x16x32_f16(al, BHr[ks][0], acc0, 0, 0, 0); \
            acc1 = __builtin_amdgcn_mfma_f32_16x16x32_f16(al, BHr[ks][1], acc1, 0, 0, 0); \
            acc2 = __builtin_amdgcn_mfma_f32_16x16x32_f16(al, BHr[ks][2], acc2, 0, 0, 0); \
            acc3 = __builtin_amdgcn_mfma_f32_16x16x32_f16(al, BHr[ks][3], acc3, 0, 0, 0); \
        }                                                                         \
        __syncthreads();                                                          \
        _Pragma("unroll")                                                         \
        for (int r = 0; r < 4; ++r) {                                             \
            int row = 4 * kg + r;                                                 \
            xw[row * 68 + mrow]      = fmaxf(acc0[r] + bj0, 0.f);                 \
            xw[row * 68 + 16 + mrow] = fmaxf(acc1[r] + bj1, 0.f);                 \
            xw[row * 68 + 32 + mrow] = fmaxf(acc2[r] + bj2, 0.f);                 \
            xw[row * 68 + 48 + mrow] = fmaxf(acc3[r] + bj3, 0.f);                 \
        }                                                                         \
        __syncthreads();                                                          \
    }

    MLP_LAYER(0, b1)
    MLP_LAYER(1, b2)
    MLP_LAYER(2, b3)
    MLP_LAYER(3, b4)
#undef MLP_LAYER

    {
        const h8* bh = reinterpret_cast<const h8*>(BH5);
        const h8* bl = reinterpret_cast<const h8*>(BL5);
        f32x4 acc = {0.f, 0.f, 0.f, 0.f};
#pragma unroll
        for (int ks = 0; ks < 2; ++ks) {
            MAKE_A(ks)
            h8 b_h = bh[ks * 64 + lane];
            h8 b_l = bl[ks * 64 + lane];
            acc = __builtin_amdgcn_mfma_f32_16x16x32_f16(ah, b_h, acc, 0, 0, 0);
            acc = __builtin_amdgcn_mfma_f32_16x16x32_f16(ah, b_l, acc, 0, 0, 0);
            acc = __builtin_amdgcn_mfma_f32_16x16x32_f16(al, b_h, acc, 0, 0, 0);
        }
        if (mrow < 11) {
            float b5v = b5[mrow];
#pragma unroll
            for (int r = 0; r < 4; ++r) {
                int node = nodeBase + 4 * kg + r;
                if (node < NN) out[(size_t)node * 11 + mrow] = acc[r] + b5v;
            }
        }
    }
}

// ---------------- launch ----------------
extern "C" void kernel_launch(void* const* d_in, const int* in_sizes, int n_in,
                              void* d_out, int out_size, void* d_ws, size_t ws_size,
                              hipStream_t stream) {
    const float* h   = (const float*)d_in[0];
    const int*   ei  = (const int*)d_in[1];
    const float* gam = (const float*)d_in[2];
    const float* bet = (const float*)d_in[3];
    const float* W1  = (const float*)d_in[4];
    const float* as1 = (const float*)d_in[5];
    const float* ad1 = (const float*)d_in[6];
    const float* b1  = (const float*)d_in[7];
    const float* W2  = (const float*)d_in[8];
    const float* as2 = (const float*)d_in[9];
    const float* ad2 = (const float*)d_in[10];
    const float* b2  = (const float*)d_in[11];
    const float* fw1 = (const float*)d_in[12];
    const float* fb1 = (const float*)d_in[13];
    const float* fw2 = (const float*)d_in[14];
    const float* fb2 = (const float*)d_in[15];
    const float* fw3 = (const float*)d_in[16];
    const float* fb3 = (const float*)d_in[17];
    const float* fw4 = (const float*)d_in[18];
    const float* fb4 = (const float*)d_in[19];
    const float* fw5 = (const float*)d_in[20];
    const float* fb5 = (const float*)d_in[21];
    float* out = (float*)d_out;

    char* ws = (char*)d_ws;
    size_t off = 0;
    auto alloc = [&](size_t bytes) -> char* {
        char* p = ws + off;
        off += (bytes + 255) & ~(size_t)255;
        return p;
    };
    float* stats  = (float*)alloc(4 * sizeof(float));
    float* coef   = (float*)alloc(8 * sizeof(float));
    int*   gcnt   = (int*)alloc(NBUCK * sizeof(int));
    int*   rowptr = (int*)alloc((size_t)(NN + 1) * sizeof(int));
    unsigned* srcl = (unsigned*)alloc((size_t)ET * sizeof(unsigned));
    float2* es2v  = (float2*)alloc((size_t)NN * sizeof(float2));
    float2* ed2v  = (float2*)alloc((size_t)NN * sizeof(float2));
    _Float16* BH  = (_Float16*)alloc(5 * 4096 * sizeof(_Float16));
    _Float16* BL  = (_Float16*)alloc(5 * 4096 * sizeof(_Float16));
    _Float16* BH5 = (_Float16*)alloc(1024 * sizeof(_Float16));
    _Float16* BL5 = (_Float16*)alloc(1024 * sizeof(_Float16));
    float* bufA   = (float*)alloc((size_t)NN * 64 * sizeof(float));   // pairs -> xph
    float* bufB   = (float*)alloc((size_t)NN * 64 * sizeof(float));
    // aliases (dead before their hosts are written):
    unsigned* pairs = (unsigned*)bufA;                    // 196*10240 u32 = 8MB; dead after k_bucket
    __half* xph   = (__half*)bufA;
    f4*     agg1a = (f4*)bufB;                            // floats [0 .. 400000)
    float2* agg1s = (float2*)(bufB + 400000);             // [400000 .. 600000)
    f4*     nd1   = (f4*)(bufB + 600000);                 // [600000 .. 1000000)
    float2* ed1   = (float2*)(bufB + 1000000);            // [1000000 .. 1200000)
    __half* yh    = (__half*)bufB;                        // written by k_gat2 (after agg dead)
    (void)ws_size; (void)in_sizes; (void)n_in; (void)out_size;

    k_setup<<<96, 256, 0, stream>>>(stats, gcnt, W1, as1, ad1, coef,
                                    W2, fw1, fw2, fw3, fw4, fw5, BH, BL, BH5, BL5);
    k_bnstats<<<64, 256, 0, stream>>>(h, stats);

    // fused CSR build + layer-1 prep
    k_fpart<<<NBLK, 256, 0, stream>>>(ei, gcnt, pairs);
    k_bucket<<<NBUCK, 512, 0, stream>>>(pairs, gcnt, rowptr, srcl,
                                        h, stats, gam, bet, coef, nd1, ed1);

    // GAT layer 1 (rank-2 path, 8 lanes/dst)
    k_gat1<<<(NN * 8 + 255) / 256, 256, 0, stream>>>(nd1, ed1, rowptr, srcl, agg1a, agg1s);

    // layer-1 finalize + MFMA layer-2 transform (writes xph fp16, es2v, ed2v)
    k_xform2m<<<(NN + 63) / 64, 256, 0, stream>>>(agg1a, agg1s, W1, b1,
                                                  BH + 4 * 4096, BL + 4 * 4096,
                                                  as2, ad2, xph, es2v, ed2v);

    // GAT layer 2: oct-edge fp16 gather, fp16 output
    k_gat2<<<(NN * 64) / 256, 256, 0, stream>>>(xph, es2v, ed2v, rowptr, srcl, b2, yh);

    // MLP head: MFMA with double-fp16 split (fp16 input)
    k_mlp<<<(NN + 63) / 64, 256, 0, stream>>>(yh, BH, BL, BH5, BL5,
                                              fb1, fb2, fb3, fb4, fb5, out);
}

// Round 25
// 145.256 us; speedup vs baseline: 1.6093x; 1.0860x over previous
//
#include <hip/hip_runtime.h>
#include <hip/hip_fp16.h>
#include <math.h>

#define NN 100000
#define EE 1600000
#define ET (EE + NN)          // edges + self loops = 1,700,000
#define NEG 0.2f
#define SMASK 0x1FFFF

// CSR-build geometry: 196 buckets x 512 dst nodes
#define NBUCK 196
#define NBLK 416              // partition blocks
#define BITEMS 4096           // items per partition block (256 thr x 16)
#define BCAP 10240            // bucket capacity (mean 8676, sigma~93)

typedef float4 f4;
typedef _Float16 h8 __attribute__((ext_vector_type(8)));
typedef float f32x4 __attribute__((ext_vector_type(4)));
typedef unsigned u32x4 __attribute__((ext_vector_type(4)));

// ---------------- setup: stats=0, gcnt=0, coef + MFMA weight packing (fused) ----------------
__global__ void k_setup(float* stats, int* gcnt,
                        const float* __restrict__ W1, const float* __restrict__ as1,
                        const float* __restrict__ ad1, float* __restrict__ coef,
                        const float* __restrict__ W2g,
                        const float* __restrict__ w1, const float* __restrict__ w2,
                        const float* __restrict__ w3, const float* __restrict__ w4,
                        const float* __restrict__ w5,
                        _Float16* __restrict__ BH, _Float16* __restrict__ BL,
                        _Float16* __restrict__ BH5, _Float16* __restrict__ BL5) {
    int idx = blockIdx.x * blockDim.x + threadIdx.x;
    if (blockIdx.x == 0) {
        int i = threadIdx.x;
        if (i < 4) stats[i] = 0.f;
        if (i < NBUCK) gcnt[i] = 0;
        if (i >= 248) {                    // threads 248..255 compute coef[0..7]
            int t = i - 248;
            int sd = t >> 2, hh = (t >> 1) & 1, c0 = t & 1;
            const float* a = sd ? ad1 : as1;
            float s = 0.f;
            for (int c = 0; c < 32; ++c) s += W1[(hh * 32 + c) * 2 + c0] * a[hh * 32 + c];
            coef[t] = s;
        }
    }
    if (idx < 5 * 4096) {
        int L = idx >> 12;
        int r = idx & 4095;
        int ks = r >> 11, nt = (r >> 9) & 3, lane = (r >> 3) & 63, j = r & 7;
        const float* W = (L == 0) ? w1 : (L == 1) ? w2 : (L == 2) ? w3 : (L == 3) ? w4 : W2g;
        int n = nt * 16 + (lane & 15);
        int k = ks * 32 + 8 * (lane >> 4) + j;
        float v = W[n * 64 + k];
        _Float16 hi = (_Float16)v;
        BH[idx] = hi;
        BL[idx] = (_Float16)(v - (float)hi);
    }
    if (idx < 1024) {
        int ks = idx >> 9, lane = (idx >> 3) & 63, j = idx & 7;
        int n = lane & 15;
        int k = ks * 32 + 8 * (lane >> 4) + j;
        float v = (n < 11) ? w5[n * 64 + k] : 0.f;
        _Float16 hi = (_Float16)v;
        BH5[idx] = hi;
        BL5[idx] = (_Float16)(v - (float)hi);
    }
}

// ---------------- BN statistics: block-level reduce, 4 atomics/block (64 blocks) ----------------
__global__ void k_bnstats(const float* __restrict__ h, float* stats) {
    __shared__ float red[16];
    int gid = blockIdx.x * blockDim.x + threadIdx.x;
    int stride = gridDim.x * blockDim.x;
    float s0 = 0.f, s1 = 0.f, q0 = 0.f, q1 = 0.f;
    for (int i = gid; i < NN; i += stride) {
        float2 v = reinterpret_cast<const float2*>(h)[i];
        s0 += v.x; q0 += v.x * v.x;
        s1 += v.y; q1 += v.y * v.y;
    }
#pragma unroll
    for (int off = 32; off >= 1; off >>= 1) {
        s0 += __shfl_xor(s0, off);
        s1 += __shfl_xor(s1, off);
        q0 += __shfl_xor(q0, off);
        q1 += __shfl_xor(q1, off);
    }
    int wv = threadIdx.x >> 6;
    if ((threadIdx.x & 63) == 0) {
        red[wv * 4 + 0] = s0; red[wv * 4 + 1] = s1;
        red[wv * 4 + 2] = q0; red[wv * 4 + 3] = q1;
    }
    __syncthreads();
    if (threadIdx.x == 0) {
        float t0 = 0.f, t1 = 0.f, t2 = 0.f, t3 = 0.f;
#pragma unroll
        for (int i = 0; i < 4; ++i) {
            t0 += red[i * 4 + 0]; t1 += red[i * 4 + 1];
            t2 += red[i * 4 + 2]; t3 += red[i * 4 + 3];
        }
        atomicAdd(&stats[0], t0); atomicAdd(&stats[1], t1);
        atomicAdd(&stats[2], t2); atomicAdd(&stats[3], t3);
    }
}

// ---------------- fused CSR partition ----------------
__global__ void __launch_bounds__(256) k_fpart(const int* __restrict__ ei, int* gcnt,
                                               unsigned* __restrict__ pairs) {
    __shared__ int hist[NBUCK];
    __shared__ int cur[NBUCK];
    int tid = threadIdx.x, blk = blockIdx.x;
    if (tid < NBUCK) hist[tid] = 0;
    int ss[16], dd[16];
    int base = blk * BITEMS;
    __syncthreads();
#pragma unroll
    for (int it = 0; it < 16; ++it) {
        int i = base + it * 256 + tid;
        int s = 0, d = -1;
        if (i < ET) {
            if (i < EE) { s = ei[i]; d = ei[EE + i]; }
            else { s = d = i - EE; }
            atomicAdd(&hist[d >> 9], 1);
        }
        ss[it] = s; dd[it] = d;
    }
    __syncthreads();
    if (tid < NBUCK) cur[tid] = tid * BCAP + atomicAdd(&gcnt[tid], hist[tid]);
    __syncthreads();
#pragma unroll
    for (int it = 0; it < 16; ++it) {
        int d = dd[it];
        if (d >= 0) {
            int pos = atomicAdd(&cur[d >> 9], 1);
            pairs[pos] = (unsigned)ss[it] | ((unsigned)(d & 511) << 17);
        }
    }
}

// ---------------- per-bucket local CSR + fused layer-1 prep ----------------
__global__ void __launch_bounds__(512) k_bucket(const unsigned* __restrict__ pairs,
                                                 const int* __restrict__ gcnt,
                                                 int* __restrict__ rowptr,
                                                 unsigned* __restrict__ srcl,
                                                 const float* __restrict__ h,
                                                 const float* __restrict__ stats,
                                                 const float* __restrict__ gamma,
                                                 const float* __restrict__ beta,
                                                 const float* __restrict__ coef,
                                                 f4* __restrict__ nd1, float2* __restrict__ ed1) {
    __shared__ int sh[512];
    __shared__ int se[512];
    int b = blockIdx.x, tid = threadIdx.x;
    sh[tid] = (tid < b) ? gcnt[tid] : 0;
    __syncthreads();
    for (int off = 256; off >= 1; off >>= 1) {
        if (tid < off) sh[tid] += sh[tid + off];
        __syncthreads();
    }
    int obase = sh[0];
    __syncthreads();
    int cnt = gcnt[b];
    int ibase = b * BCAP;
    sh[tid] = 0;
    __syncthreads();
    for (int k = tid; k < cnt; k += 512) atomicAdd(&sh[pairs[ibase + k] >> 17], 1);
    __syncthreads();
    int deg = sh[tid];
    se[tid] = deg;
    __syncthreads();
    for (int off = 1; off < 512; off <<= 1) {
        int t = (tid >= off) ? se[tid - off] : 0;
        __syncthreads();
        se[tid] += t;
        __syncthreads();
    }
    int excl = se[tid] - deg;
    int node = (b << 9) + tid;
    if (node < NN) rowptr[node] = obase + excl;
    sh[tid] = obase + excl;     // cursor
    __syncthreads();
    for (int k = tid; k < cnt; k += 512) {
        unsigned p = pairs[ibase + k];
        int pos = atomicAdd(&sh[p >> 17], 1);
        srcl[pos] = p;
    }
    if (b == 0 && tid == 0) rowptr[NN] = ET;

    // fused layer-1 prep
    if (node < NN) {
        const float inv = 1.f / (float)NN;
        float mu0 = stats[0] * inv, mu1 = stats[1] * inv;
        float v0 = stats[2] * inv - mu0 * mu0;
        float v1 = stats[3] * inv - mu1 * mu1;
        float g0 = rsqrtf(v0 + 1e-5f) * gamma[0];
        float g1 = rsqrtf(v1 + 1e-5f) * gamma[1];
        float2 hv = reinterpret_cast<const float2*>(h)[node];
        float x0 = (hv.x - mu0) * g0 + beta[0];
        float x1 = (hv.y - mu1) * g1 + beta[1];
        nd1[node] = make_float4(x0 * coef[0] + x1 * coef[1], x0 * coef[2] + x1 * coef[3], x0, x1);
        ed1[node] = make_float2(x0 * coef[4] + x1 * coef[5], x0 * coef[6] + x1 * coef[7]);
    }
}

// ---------------- layer-1 GAT: 8 lanes per dst, shfl reduce ----------------
__global__ void __launch_bounds__(256) k_gat1(
    const f4* __restrict__ nd1, const float2* __restrict__ ed1,
    const int* __restrict__ rowptr, const unsigned* __restrict__ srcl,
    f4* __restrict__ agg1a, float2* __restrict__ agg1s) {
    int gid = blockIdx.x * blockDim.x + threadIdx.x;
    int n = gid >> 3;
    int sub = gid & 7;
    if (n >= NN) return;
    int beg = rowptr[n], end = rowptr[n + 1];
    float2 ed = ed1[n];
    float A0 = 0.f, B0 = 0.f, S0 = 0.f, A1 = 0.f, B1 = 0.f, S1 = 0.f;
    for (int k = beg + sub; k < end; k += 8) {
        int s = (int)(srcl[k] & SMASK);
        f4 p = nd1[s];
        float e0 = p.x + ed.x;
        float e1 = p.y + ed.y;
        e0 = fmaxf(e0, NEG * e0);
        e1 = fmaxf(e1, NEG * e1);
        float w0 = __expf(e0);
        float w1 = __expf(e1);
        A0 += w0 * p.z; B0 += w0 * p.w; S0 += w0;
        A1 += w1 * p.z; B1 += w1 * p.w; S1 += w1;
    }
#pragma unroll
    for (int off = 1; off < 8; off <<= 1) {
        A0 += __shfl_xor(A0, off);
        B0 += __shfl_xor(B0, off);
        S0 += __shfl_xor(S0, off);
        A1 += __shfl_xor(A1, off);
        B1 += __shfl_xor(B1, off);
        S1 += __shfl_xor(S1, off);
    }
    if (sub == 0) {
        agg1a[n] = make_float4(A0, B0, A1, B1);
        agg1s[n] = make_float2(S0, S1);
    }
}

#define MAKE_A(ks)                                                                \
    f4 a0 = *reinterpret_cast<const f4*>(&xw[mrow * 68 + kg * 8 + (ks) * 32]);    \
    f4 a1 = *reinterpret_cast<const f4*>(&xw[mrow * 68 + kg * 8 + (ks) * 32 + 4]);\
    float av0 = a0.x, av1 = a0.y, av2 = a0.z, av3 = a0.w;                         \
    float av4 = a1.x, av5 = a1.y, av6 = a1.z, av7 = a1.w;                         \
    h8 ah, al;                                                                    \
    { _Float16 t;                                                                 \
      t = (_Float16)av0; ah[0] = t; al[0] = (_Float16)(av0 - (float)t);           \
      t = (_Float16)av1; ah[1] = t; al[1] = (_Float16)(av1 - (float)t);           \
      t = (_Float16)av2; ah[2] = t; al[2] = (_Float16)(av2 - (float)t);           \
      t = (_Float16)av3; ah[3] = t; al[3] = (_Float16)(av3 - (float)t);           \
      t = (_Float16)av4; ah[4] = t; al[4] = (_Float16)(av4 - (float)t);           \
      t = (_Float16)av5; ah[5] = t; al[5] = (_Float16)(av5 - (float)t);           \
      t = (_Float16)av6; ah[6] = t; al[6] = (_Float16)(av6 - (float)t);           \
      t = (_Float16)av7; ah[7] = t; al[7] = (_Float16)(av7 - (float)t); }

// ---------------- layer-1 finalize + MFMA linear(64->64) + layer-2 attn scalars ----------------
__global__ void __launch_bounds__(256) k_xform2m(
    const f4* __restrict__ agg1a, const float2* __restrict__ agg1s,
    const float* __restrict__ W1, const float* __restrict__ b1,
    const _Float16* __restrict__ BH2, const _Float16* __restrict__ BL2,
    const float* __restrict__ a_s, const float* __restrict__ a_d,
    __half* __restrict__ xph, float2* __restrict__ es2v, float2* __restrict__ ed2v) {
    __shared__ float xs[4 * 1088];
    int lane = threadIdx.x & 63;
    int w = threadIdx.x >> 6;
    float* xw = &xs[w * 1088];
    int nodeBase = blockIdx.x * 64 + w * 16;
    int mrow = lane & 15;
    int kg = lane >> 4;
    int n = nodeBase + mrow;

    f4 ag = make_float4(0.f, 0.f, 0.f, 0.f);
    float2 sg = make_float2(1.f, 1.f);
    if (n < NN) { ag = agg1a[n]; sg = agg1s[n]; }
    float r0 = 1.f / (sg.x + 1e-16f);
    float r1 = 1.f / (sg.y + 1e-16f);
#pragma unroll
    for (int j = 0; j < 16; ++j) {
        int f = kg * 16 + j;
        float A = (f < 32) ? ag.x : ag.z;
        float B = (f < 32) ? ag.y : ag.w;
        float r = (f < 32) ? r0 : r1;
        xw[mrow * 68 + f] = fmaxf((A * W1[2 * f] + B * W1[2 * f + 1]) * r + b1[f], 0.f);
    }
    __syncthreads();

    const h8* bh = reinterpret_cast<const h8*>(BH2);
    const h8* bl = reinterpret_cast<const h8*>(BL2);
    h8 BHr[2][4], BLr[2][4];
#pragma unroll
    for (int ks = 0; ks < 2; ++ks)
#pragma unroll
        for (int nt = 0; nt < 4; ++nt) {
            BHr[ks][nt] = bh[(ks * 4 + nt) * 64 + lane];
            BLr[ks][nt] = bl[(ks * 4 + nt) * 64 + lane];
        }
    f32x4 acc0 = {0.f, 0.f, 0.f, 0.f}, acc1 = acc0, acc2 = acc0, acc3 = acc0;
#pragma unroll
    for (int ks = 0; ks < 2; ++ks) {
        MAKE_A(ks)
        acc0 = __builtin_amdgcn_mfma_f32_16x16x32_f16(ah, BHr[ks][0], acc0, 0, 0, 0);
        acc1 = __builtin_amdgcn_mfma_f32_16x16x32_f16(ah, BHr[ks][1], acc1, 0, 0, 0);
        acc2 = __builtin_amdgcn_mfma_f32_16x16x32_f16(ah, BHr[ks][2], acc2, 0, 0, 0);
        acc3 = __builtin_amdgcn_mfma_f32_16x16x32_f16(ah, BHr[ks][3], acc3, 0, 0, 0);
        acc0 = __builtin_amdgcn_mfma_f32_16x16x32_f16(ah, BLr[ks][0], acc0, 0, 0, 0);
        acc1 = __builtin_amdgcn_mfma_f32_16x16x32_f16(ah, BLr[ks][1], acc1, 0, 0, 0);
        acc2 = __builtin_amdgcn_mfma_f32_16x16x32_f16(ah, BLr[ks][2], acc2, 0, 0, 0);
        acc3 = __builtin_amdgcn_mfma_f32_16x16x32_f16(ah, BLr[ks][3], acc3, 0, 0, 0);
        acc0 = __builtin_amdgcn_mfma_f32_16x16x32_f16(al, BHr[ks][0], acc0, 0, 0, 0);
        acc1 = __builtin_amdgcn_mfma_f32_16x16x32_f16(al, BHr[ks][1], acc1, 0, 0, 0);
        acc2 = __builtin_amdgcn_mfma_f32_16x16x32_f16(al, BHr[ks][2], acc2, 0, 0, 0);
        acc3 = __builtin_amdgcn_mfma_f32_16x16x32_f16(al, BHr[ks][3], acc3, 0, 0, 0);
    }
    __syncthreads();
#pragma unroll
    for (int r = 0; r < 4; ++r) {
        int row = 4 * kg + r;
        xw[row * 68 + mrow]      = acc0[r];
        xw[row * 68 + 16 + mrow] = acc1[r];
        xw[row * 68 + 32 + mrow] = acc2[r];
        xw[row * 68 + 48 + mrow] = acc3[r];
    }
    __syncthreads();

    float ps = 0.f, pd = 0.f;
#pragma unroll
    for (int j = 0; j < 16; ++j) {
        int f = kg * 16 + j;
        float v = xw[mrow * 68 + f];
        ps += v * a_s[f];
        pd += v * a_d[f];
    }
    ps += __shfl_xor(ps, 16);
    pd += __shfl_xor(pd, 16);
    float psB = __shfl_xor(ps, 32);
    float pdB = __shfl_xor(pd, 32);
    if (kg == 0 && n < NN) {
        es2v[n] = make_float2(ps, psB);
        ed2v[n] = make_float2(pd, pdB);
    }

#pragma unroll
    for (int i = 0; i < 8; ++i) {
        int idx = lane + 64 * i;
        int nl = idx >> 5;
        int c = idx & 31;
        int g = nodeBase + nl;
        if (g < NN) {
            __half2 hv = __floats2half2_rn(xw[nl * 68 + 2 * c], xw[nl * 68 + 2 * c + 1]);
            *reinterpret_cast<__half2*>(&xph[(size_t)g * 64 + 2 * c]) = hv;
        }
    }
}

// ---------------- layer-2 GAT: OCT edges, fp16 in/out ----------------
__global__ void __launch_bounds__(256) k_gat2(
    const __half* __restrict__ xph, const float2* __restrict__ es2v,
    const float2* __restrict__ ed2v,
    const int* __restrict__ rowptr, const unsigned* __restrict__ srcl,
    const float* __restrict__ bias, __half* __restrict__ yh) {
    int wid = (blockIdx.x * blockDim.x + threadIdx.x) >> 6;
    int lane = threadIdx.x & 63;
    if (wid >= NN) return;
    int g = lane >> 3;            // edge slot within octet (0..7)
    int t = lane & 7;             // channel octet index: channels 8t..8t+7
    bool hh = t >= 4;             // head 1 for channels >= 32
    int ch = 8 * t;
    float2 edp = ed2v[wid];
    float edv = hh ? edp.y : edp.x;
    int beg = rowptr[wid], end = rowptr[wid + 1];
    float sum = 0.f;
    float a0 = 0.f, a1 = 0.f, a2 = 0.f, a3 = 0.f;
    float a4 = 0.f, a5 = 0.f, a6 = 0.f, a7 = 0.f;
    int k = beg;

#define GO(kk)                                                                    \
    {                                                                             \
        int s_ = (int)(srcl[(kk) + g] & SMASK);                                   \
        float2 ep_ = es2v[s_];                                                    \
        u32x4 xr_ = *reinterpret_cast<const u32x4*>(&xph[(size_t)s_ * 64 + ch]);  \
        float e_ = (hh ? ep_.y : ep_.x) + edv;                                    \
        e_ = fmaxf(e_, NEG * e_);                                                 \
        float w_ = __expf(e_);                                                    \
        unsigned q0_ = xr_.x, q1_ = xr_.y, q2_ = xr_.z, q3_ = xr_.w;              \
        float2 p0_ = __half22float2(*reinterpret_cast<const __half2*>(&q0_));     \
        float2 p1_ = __half22float2(*reinterpret_cast<const __half2*>(&q1_));     \
        float2 p2_ = __half22float2(*reinterpret_cast<const __half2*>(&q2_));     \
        float2 p3_ = __half22float2(*reinterpret_cast<const __half2*>(&q3_));     \
        sum += w_;                                                                \
        a0 += w_ * p0_.x; a1 += w_ * p0_.y; a2 += w_ * p1_.x; a3 += w_ * p1_.y;   \
        a4 += w_ * p2_.x; a5 += w_ * p2_.y; a6 += w_ * p3_.x; a7 += w_ * p3_.y;   \
    }

    for (; k + 16 <= end; k += 16) {
        GO(k) GO(k + 8)
    }
    for (; k + 8 <= end; k += 8) {
        GO(k)
    }
    if (k < end) {                 // masked tail (1..7 edges)
        int idx = k + g;
        bool valid = idx < end;
        int s_ = (int)(srcl[valid ? idx : k] & SMASK);
        float2 ep_ = es2v[s_];
        u32x4 xr_ = *reinterpret_cast<const u32x4*>(&xph[(size_t)s_ * 64 + ch]);
        float e_ = (hh ? ep_.y : ep_.x) + edv;
        e_ = fmaxf(e_, NEG * e_);
        float w_ = valid ? __expf(e_) : 0.f;
        unsigned q0_ = xr_.x, q1_ = xr_.y, q2_ = xr_.z, q3_ = xr_.w;
        float2 p0_ = __half22float2(*reinterpret_cast<const __half2*>(&q0_));
        float2 p1_ = __half22float2(*reinterpret_cast<const __half2*>(&q1_));
        float2 p2_ = __half22float2(*reinterpret_cast<const __half2*>(&q2_));
        float2 p3_ = __half22float2(*reinterpret_cast<const __half2*>(&q3_));
        sum += w_;
        a0 += w_ * p0_.x; a1 += w_ * p0_.y; a2 += w_ * p1_.x; a3 += w_ * p1_.y;
        a4 += w_ * p2_.x; a5 += w_ * p2_.y; a6 += w_ * p3_.x; a7 += w_ * p3_.y;
    }
#undef GO

#pragma unroll
    for (int off = 8; off <= 32; off <<= 1) {
        sum += __shfl_xor(sum, off);
        a0 += __shfl_xor(a0, off); a1 += __shfl_xor(a1, off);
        a2 += __shfl_xor(a2, off); a3 += __shfl_xor(a3, off);
        a4 += __shfl_xor(a4, off); a5 += __shfl_xor(a5, off);
        a6 += __shfl_xor(a6, off); a7 += __shfl_xor(a7, off);
    }
    if (lane < 8) {
        float rs = 1.f / (sum + 1e-16f);
        __half2 o0 = __floats2half2_rn(fmaxf(a0 * rs + bias[ch], 0.f),
                                       fmaxf(a1 * rs + bias[ch + 1], 0.f));
        __half2 o1 = __floats2half2_rn(fmaxf(a2 * rs + bias[ch + 2], 0.f),
                                       fmaxf(a3 * rs + bias[ch + 3], 0.f));
        __half2 o2 = __floats2half2_rn(fmaxf(a4 * rs + bias[ch + 4], 0.f),
                                       fmaxf(a5 * rs + bias[ch + 5], 0.f));
        __half2 o3 = __floats2half2_rn(fmaxf(a6 * rs + bias[ch + 6], 0.f),
                                       fmaxf(a7 * rs + bias[ch + 7], 0.f));
        u32x4 pk;
        pk.x = *reinterpret_cast<unsigned*>(&o0);
        pk.y = *reinterpret_cast<unsigned*>(&o1);
        pk.z = *reinterpret_cast<unsigned*>(&o2);
        pk.w = *reinterpret_cast<unsigned*>(&o3);
        *reinterpret_cast<u32x4*>(&yh[(size_t)wid * 64 + ch]) = pk;
    }
}

// ---------------- fused MLP via MFMA (double-fp16 split), fp16 input ----------------
__global__ void __launch_bounds__(256) k_mlp(
    const __half* __restrict__ hin,
    const _Float16* __restrict__ BH, const _Float16* __restrict__ BL,
    const _Float16* __restrict__ BH5, const _Float16* __restrict__ BL5,
    const float* __restrict__ b1, const float* __restrict__ b2,
    const float* __restrict__ b3, const float* __restrict__ b4,
    const float* __restrict__ b5,
    float* __restrict__ out) {
    __shared__ float xs[4 * 16 * 68];
    int lane = threadIdx.x & 63;
    int w = threadIdx.x >> 6;
    float* xw = &xs[w * 1088];
    int nodeBase = blockIdx.x * 64 + w * 16;
    int mrow = lane & 15;
    int kg = lane >> 4;

#pragma unroll
    for (int i = 0; i < 2; ++i) {
        int idx = lane + 64 * i;       // 0..127 (16 nodes x 8 octets)
        int nl = idx >> 3;
        int c8 = (idx & 7) * 8;
        u32x4 t = {0u, 0u, 0u, 0u};
        if (nodeBase + nl < NN)
            t = *reinterpret_cast<const u32x4*>(&hin[(size_t)(nodeBase + nl) * 64 + c8]);
        unsigned q0 = t.x, q1 = t.y, q2 = t.z, q3 = t.w;
        float2 p0 = __half22float2(*reinterpret_cast<const __half2*>(&q0));
        float2 p1 = __half22float2(*reinterpret_cast<const __half2*>(&q1));
        float2 p2 = __half22float2(*reinterpret_cast<const __half2*>(&q2));
        float2 p3 = __half22float2(*reinterpret_cast<const __half2*>(&q3));
        f4 lo = make_float4(p0.x, p0.y, p1.x, p1.y);
        f4 hi = make_float4(p2.x, p2.y, p3.x, p3.y);
        *reinterpret_cast<f4*>(&xw[nl * 68 + c8]) = lo;
        *reinterpret_cast<f4*>(&xw[nl * 68 + c8 + 4]) = hi;
    }
    __syncthreads();

#define MLP_LAYER(L, Bp)                                                          \
    {                                                                             \
        const h8* bh = reinterpret_cast<const h8*>(BH + (L) * 4096);              \
        const h8* bl = reinterpret_cast<const h8*>(BL + (L) * 4096);              \
        h8 BHr[2][4], BLr[2][4];                                                  \
        _Pragma("unroll")                                                         \
        for (int ks = 0; ks < 2; ++ks)                                            \
            _Pragma("unroll")                                                     \
            for (int nt = 0; nt < 4; ++nt) {                                      \
                BHr[ks][nt] = bh[(ks * 4 + nt) * 64 + lane];                      \
                BLr[ks][nt] = bl[(ks * 4 + nt) * 64 + lane];                      \
            }                                                                     \
        float bj0 = Bp[mrow], bj1 = Bp[16 + mrow];                                \
        float bj2 = Bp[32 + mrow], bj3 = Bp[48 + mrow];                           \
        f32x4 acc0 = {0.f, 0.f, 0.f, 0.f}, acc1 = acc0, acc2 = acc0, acc3 = acc0; \
        _Pragma("unroll")                                                         \
        for (int ks = 0; ks < 2; ++ks) {                                          \
            MAKE_A(ks)                                                            \
            acc0 = __builtin_amdgcn_mfma_f32_16x16x32_f16(ah, BHr[ks][0], acc0, 0, 0, 0); \
            acc1 = __builtin_amdgcn_mfma_f32_16x16x32_f16(ah, BHr[ks][1], acc1, 0, 0, 0); \
            acc2 = __builtin_amdgcn_mfma_f32_16x16x32_f16(ah, BHr[ks][2], acc2, 0, 0, 0); \
            acc3 = __builtin_amdgcn_mfma_f32_16x16x32_f16(ah, BHr[ks][3], acc3, 0, 0, 0); \
            acc0 = __builtin_amdgcn_mfma_f32_16x16x32_f16(ah, BLr[ks][0], acc0, 0, 0, 0); \
            acc1 = __builtin_amdgcn_mfma_f32_16x16x32_f16(ah, BLr[ks][1], acc1, 0, 0, 0); \
            acc2 = __builtin_amdgcn_mfma_f32_16x16x32_f16(ah, BLr[ks][2], acc2, 0, 0, 0); \
            acc3 = __builtin_amdgcn_mfma_f32_16x16x32_f16(ah, BLr[ks][3], acc3, 0, 0, 0); \
            acc0 = __builtin_amdgcn_mfma_f32_16x16x32_f16(al, BHr[ks][0], acc0, 0, 0, 0); \
            acc1 = __builtin_amdgcn_mfma_f32_16x16x32_f16(al, BHr[ks][1], acc1, 0, 0, 0); \
            acc2 = __builtin_amdgcn_mfma_f32_16x16x32_f16(al, BHr[ks][2], acc2, 0, 0, 0); \
            acc3 = __builtin_amdgcn_mfma_f32_16x16x32_f16(al, BHr[ks][3], acc3, 0, 0, 0); \
        }                                                                         \
        __syncthreads();                                                          \
        _Pragma("unroll")                                                         \
        for (int r = 0; r < 4; ++r) {                                             \
            int row = 4 * kg + r;                                                 \
            xw[row * 68 + mrow]      = fmaxf(acc0[r] + bj0, 0.f);                 \
            xw[row * 68 + 16 + mrow] = fmaxf(acc1[r] + bj1, 0.f);                 \
            xw[row * 68 + 32 + mrow] = fmaxf(acc2[r] + bj2, 0.f);                 \
            xw[row * 68 + 48 + mrow] = fmaxf(acc3[r] + bj3, 0.f);                 \
        }                                                                         \
        __syncthreads();                                                          \
    }

    MLP_LAYER(0, b1)
    MLP_LAYER(1, b2)
    MLP_LAYER(2, b3)
    MLP_LAYER(3, b4)
#undef MLP_LAYER

    {
        const h8* bh = reinterpret_cast<const h8*>(BH5);
        const h8* bl = reinterpret_cast<const h8*>(BL5);
        f32x4 acc = {0.f, 0.f, 0.f, 0.f};
#pragma unroll
        for (int ks = 0; ks < 2; ++ks) {
            MAKE_A(ks)
            h8 b_h = bh[ks * 64 + lane];
            h8 b_l = bl[ks * 64 + lane];
            acc = __builtin_amdgcn_mfma_f32_16x16x32_f16(ah, b_h, acc, 0, 0, 0);
            acc = __builtin_amdgcn_mfma_f32_16x16x32_f16(ah, b_l, acc, 0, 0, 0);
            acc = __builtin_amdgcn_mfma_f32_16x16x32_f16(al, b_h, acc, 0, 0, 0);
        }
        if (mrow < 11) {
            float b5v = b5[mrow];
#pragma unroll
            for (int r = 0; r < 4; ++r) {
                int node = nodeBase + 4 * kg + r;
                if (node < NN) out[(size_t)node * 11 + mrow] = acc[r] + b5v;
            }
        }
    }
}

// ---------------- launch ----------------
extern "C" void kernel_launch(void* const* d_in, const int* in_sizes, int n_in,
                              void* d_out, int out_size, void* d_ws, size_t ws_size,
                              hipStream_t stream) {
    const float* h   = (const float*)d_in[0];
    const int*   ei  = (const int*)d_in[1];
    const float* gam = (const float*)d_in[2];
    const float* bet = (const float*)d_in[3];
    const float* W1  = (const float*)d_in[4];
    const float* as1 = (const float*)d_in[5];
    const float* ad1 = (const float*)d_in[6];
    const float* b1  = (const float*)d_in[7];
    const float* W2  = (const float*)d_in[8];
    const float* as2 = (const float*)d_in[9];
    const float* ad2 = (const float*)d_in[10];
    const float* b2  = (const float*)d_in[11];
    const float* fw1 = (const float*)d_in[12];
    const float* fb1 = (const float*)d_in[13];
    const float* fw2 = (const float*)d_in[14];
    const float* fb2 = (const float*)d_in[15];
    const float* fw3 = (const float*)d_in[16];
    const float* fb3 = (const float*)d_in[17];
    const float* fw4 = (const float*)d_in[18];
    const float* fb4 = (const float*)d_in[19];
    const float* fw5 = (const float*)d_in[20];
    const float* fb5 = (const float*)d_in[21];
    float* out = (float*)d_out;

    char* ws = (char*)d_ws;
    size_t off = 0;
    auto alloc = [&](size_t bytes) -> char* {
        char* p = ws + off;
        off += (bytes + 255) & ~(size_t)255;
        return p;
    };
    float* stats  = (float*)alloc(4 * sizeof(float));
    float* coef   = (float*)alloc(8 * sizeof(float));
    int*   gcnt   = (int*)alloc(NBUCK * sizeof(int));
    int*   rowptr = (int*)alloc((size_t)(NN + 1) * sizeof(int));
    unsigned* srcl = (unsigned*)alloc((size_t)ET * sizeof(unsigned));
    float2* es2v  = (float2*)alloc((size_t)NN * sizeof(float2));
    float2* ed2v  = (float2*)alloc((size_t)NN * sizeof(float2));
    _Float16* BH  = (_Float16*)alloc(5 * 4096 * sizeof(_Float16));
    _Float16* BL  = (_Float16*)alloc(5 * 4096 * sizeof(_Float16));
    _Float16* BH5 = (_Float16*)alloc(1024 * sizeof(_Float16));
    _Float16* BL5 = (_Float16*)alloc(1024 * sizeof(_Float16));
    float* bufA   = (float*)alloc((size_t)NN * 64 * sizeof(float));   // pairs -> xph
    float* bufB   = (float*)alloc((size_t)NN * 64 * sizeof(float));
    // aliases (dead before their hosts are written):
    unsigned* pairs = (unsigned*)bufA;                    // 196*10240 u32 = 8MB; dead after k_bucket
    __half* xph   = (__half*)bufA;
    f4*     agg1a = (f4*)bufB;                            // floats [0 .. 400000)
    float2* agg1s = (float2*)(bufB + 400000);             // [400000 .. 600000)
    f4*     nd1   = (f4*)(bufB + 600000);                 // [600000 .. 1000000)
    float2* ed1   = (float2*)(bufB + 1000000);            // [1000000 .. 1200000)
    __half* yh    = (__half*)bufB;                        // written by k_gat2 (after agg dead)
    (void)ws_size; (void)in_sizes; (void)n_in; (void)out_size;

    k_setup<<<96, 256, 0, stream>>>(stats, gcnt, W1, as1, ad1, coef,
                                    W2, fw1, fw2, fw3, fw4, fw5, BH, BL, BH5, BL5);
    k_bnstats<<<64, 256, 0, stream>>>(h, stats);

    // fused CSR build + layer-1 prep
    k_fpart<<<NBLK, 256, 0, stream>>>(ei, gcnt, pairs);
    k_bucket<<<NBUCK, 512, 0, stream>>>(pairs, gcnt, rowptr, srcl,
                                        h, stats, gam, bet, coef, nd1, ed1);

    // GAT layer 1 (rank-2 path, 8 lanes/dst)
    k_gat1<<<(NN * 8 + 255) / 256, 256, 0, stream>>>(nd1, ed1, rowptr, srcl, agg1a, agg1s);

    // layer-1 finalize + MFMA layer-2 transform (writes xph fp16, es2v, ed2v)
    k_xform2m<<<(NN + 63) / 64, 256, 0, stream>>>(agg1a, agg1s, W1, b1,
                                                  BH + 4 * 4096, BL + 4 * 4096,
                                                  as2, ad2, xph, es2v, ed2v);

    // GAT layer 2: oct-edge fp16 gather, fp16 output
    k_gat2<<<(NN * 64) / 256, 256, 0, stream>>>(xph, es2v, ed2v, rowptr, srcl, b2, yh);

    // MLP head: MFMA with double-fp16 split (fp16 input)
    k_mlp<<<(NN + 63) / 64, 256, 0, stream>>>(yh, BH, BL, BH5, BL5,
                                              fb1, fb2, fb3, fb4, fb5, out);
}